// Round 7
// baseline (408.123 us; speedup 1.0000x reference)
//
#include <hip/hip_runtime.h>
#include <stdint.h>

#define BB 32
#define SS 512
#define DD 640
#define HH 10
#define DKK 64
#define NTOK (BB*SS)   // 16384

using f32x4  = __attribute__((ext_vector_type(4))) float;
using bf16x8 = __attribute__((ext_vector_type(8))) __bf16;
using u32x4  = __attribute__((ext_vector_type(4))) unsigned int;
using u32x2  = __attribute__((ext_vector_type(2))) unsigned int;
using u16x4  = __attribute__((ext_vector_type(4))) unsigned short;
using i32x4  = __attribute__((ext_vector_type(4))) int;

__device__ inline unsigned short f2bf(float f){
  union { float f; unsigned int u; } v; v.f=f;
  unsigned int u=v.u;
  u += 0x7FFFu + ((u>>16)&1u);
  return (unsigned short)(u>>16);
}
__device__ inline float bf2f(unsigned short s){
  union { unsigned int u; float f; } v; v.u = ((unsigned int)s)<<16;
  return v.f;
}
__device__ inline unsigned int cvtpk_bf16(float lo, float hi){
  unsigned int r;
  asm volatile("v_cvt_pk_bf16_f32 %0, %1, %2" : "=v"(r) : "v"(lo), "v"(hi));
  return r;
}
__device__ inline void gload_lds16(const unsigned short* g, unsigned short* l){
  __builtin_amdgcn_global_load_lds(
      (const __attribute__((address_space(1))) unsigned int*)g,
      (__attribute__((address_space(3))) unsigned int*)l, 16, 0, 0);
}

// ---------------- conversions ----------------
__global__ void convert_qkv(const float* __restrict__ q, const float* __restrict__ k,
                            const float* __restrict__ v,
                            unsigned short* __restrict__ xq, unsigned short* __restrict__ xk,
                            unsigned short* __restrict__ xv){
  int i = blockIdx.x*blockDim.x + threadIdx.x;
  const int n4 = (NTOK*DD)/4;
  for (; i < n4; i += gridDim.x*blockDim.x){
    f32x4 a = ((const f32x4*)q)[i];
    f32x4 b = ((const f32x4*)k)[i];
    f32x4 c = ((const f32x4*)v)[i];
    u16x4 ra, rb, rc;
    #pragma unroll
    for (int j=0;j<4;j++){ ra[j]=f2bf(a[j]); rb[j]=f2bf(b[j]); rc[j]=f2bf(c[j]); }
    ((u16x4*)xq)[i]=ra; ((u16x4*)xk)[i]=rb; ((u16x4*)xv)[i]=rc;
  }
}

__global__ void convert_w(const float* __restrict__ wq, const float* __restrict__ wk,
                          const float* __restrict__ wv, const float* __restrict__ rw,
                          unsigned short* __restrict__ bwq, unsigned short* __restrict__ bwk,
                          unsigned short* __restrict__ bwv, unsigned short* __restrict__ brw,
                          unsigned short* __restrict__ brwt){
  int i = blockIdx.x*blockDim.x + threadIdx.x;
  if (i < DD*DD){
    bwq[i]=f2bf(wq[i]); bwk[i]=f2bf(wk[i]); bwv[i]=f2bf(wv[i]);
    unsigned short r = f2bf(rw[i]);
    brw[i]=r;
    int ri = i / DD, o = i % DD;
    brwt[o*DD + ri] = r;
  }
}

// bias in 16x16-tile layout: biasT[((b*32 + q>>4)*32 + k>>4)*256 + (q&15)*16 + (k&15)]
__global__ void bias_kernel(const int* __restrict__ mask, const float* __restrict__ adj,
                            const int* __restrict__ layer, unsigned short* __restrict__ biasT){
  float sc = 1.0f/(float)(layer[0]+1);
  int i = blockIdx.x*blockDim.x + threadIdx.x;
  const int n4 = (BB*SS*SS)/4;
  for (; i < n4; i += gridDim.x*blockDim.x){
    i32x4 m = ((const i32x4*)mask)[i];
    f32x4 a = ((const f32x4*)adj)[i];
    u16x4 r;
    #pragma unroll
    for (int j=0;j<4;j++) r[j] = m[j] ? f2bf(a[j]*sc) : f2bf(-1e9f);
    const int e  = i*4;
    const int bb = e >> 18;
    const int qq = (e >> 9) & 511;
    const int kk = e & 511;
    const int idx = (((bb*32 + (qq>>4))*32 + (kk>>4))<<8) + ((qq&15)<<4) + (kk&15);
    *(u16x4*)(biasT + idx) = r;
  }
}

// ---------------- wide GEMM core (BM=64, BN=640, BK=32, 512 threads) ----------
// Single-buffered LDS (44KB -> 2 blocks/CU); m97 2-barrier loop, cross-block overlap.
// Swizzle: stored unit u of row r holds logical octet u ^ ((r>>1)&3) -> b128 reads
// hit every (parity,unit) pair exactly 8x = conflict-free floor.
template<bool SWAP>
__device__ inline void wide_gemm(const unsigned short* __restrict__ A,
                                 const unsigned short* __restrict__ W,
                                 int m0, f32x4 (&acc)[2][10])
{
  __shared__ unsigned short As[64*32];    // 4KB
  __shared__ unsigned short Bs[640*32];   // 40KB
  const int tid  = threadIdx.x;
  const int lane = tid & 63;
  const int wave = tid >> 6;      // 0..7
  const int wm   = wave >> 2;     // 0..1
  const int wn   = wave & 3;      // 0..3
  const int l15  = lane & 15;
  const int g    = lane >> 4;

  const int srow  = lane >> 2;                      // 0..15
  const int sunit = (lane & 3) ^ ((lane >> 3) & 3); // pre-swizzled source octet
  const unsigned short* Ag = A + (int64_t)(m0 + (wave&3)*16 + srow)*DD + sunit*8;
  const unsigned short* Wg = W + (int64_t)(wave*80 + srow)*DD + sunit*8;

  auto stage = [&](int k0){
    if (wave < 4)
      gload_lds16(Ag + k0, &As[wave*512]);
    #pragma unroll
    for (int c=0;c<5;c++)
      gload_lds16(Wg + (int64_t)(c*16)*DD + k0, &Bs[wave*2560 + c*512]);
  };

  const int fro = (g ^ ((l15 >> 1) & 3)) * 8;    // swizzled read offset within row

  for (int k0 = 0; k0 < DD; k0 += 32){
    stage(k0);
    __syncthreads();               // drains vmcnt -> LDS tiles ready
    bf16x8 af[2], wf[10];
    #pragma unroll
    for (int mi=0;mi<2;mi++) af[mi] = *(const bf16x8*)&As[(wm*32 + mi*16 + l15)*32 + fro];
    #pragma unroll
    for (int ni=0;ni<10;ni++) wf[ni] = *(const bf16x8*)&Bs[(wn*160 + ni*16 + l15)*32 + fro];
    #pragma unroll
    for (int mi=0;mi<2;mi++)
      #pragma unroll
      for (int ni=0;ni<10;ni++){
        if constexpr (SWAP)
          acc[mi][ni] = __builtin_amdgcn_mfma_f32_16x16x32_bf16(wf[ni], af[mi], acc[mi][ni], 0,0,0);
        else
          acc[mi][ni] = __builtin_amdgcn_mfma_f32_16x16x32_bf16(af[mi], wf[ni], acc[mi][ni], 0,0,0);
      }
    __syncthreads();               // readers done before next stage overwrites
  }
}

// q/k projection: SWAP layout, out bf16 [b,h,s,dk], 8B stores over consecutive dk
__global__ __launch_bounds__(512,2)
void qk_wide(const unsigned short* __restrict__ Xq, const unsigned short* __restrict__ Xk,
             const unsigned short* __restrict__ bWq, const unsigned short* __restrict__ bWk,
             const float* __restrict__ bq, const float* __restrict__ bk,
             unsigned short* __restrict__ qbuf, unsigned short* __restrict__ kbuf)
{
  const int sel = blockIdx.y;
  const unsigned short* A = sel ? Xk : Xq;
  const unsigned short* W = sel ? bWk : bWq;
  const float* bias       = sel ? bk : bq;
  unsigned short* dst     = sel ? kbuf : qbuf;
  const int m0 = blockIdx.x * 64;

  f32x4 acc[2][10];
  #pragma unroll
  for (int i=0;i<2;i++)
    #pragma unroll
    for (int j=0;j<10;j++){ f32x4 z={0.f,0.f,0.f,0.f}; acc[i][j]=z; }
  wide_gemm<true>(A, W, m0, acc);

  const int lane = threadIdx.x & 63, wave = threadIdx.x >> 6;
  const int wm = wave>>2, wn = wave&3, l15 = lane&15, g = lane>>4;
  #pragma unroll
  for (int mi=0;mi<2;mi++){
    const int token = m0 + wm*32 + mi*16 + l15;
    const int bb = token >> 9, s = token & 511;
    #pragma unroll
    for (int ni=0;ni<10;ni++){
      const int col0 = wn*160 + ni*16 + g*4;
      const int h = col0 >> 6, dk0 = col0 & 63;
      f32x4 bv = *(const f32x4*)(bias + col0);
      f32x4 v = acc[mi][ni];
      u32x2 w;
      w[0] = cvtpk_bf16(v[0]+bv[0], v[1]+bv[1]);
      w[1] = cvtpk_bf16(v[2]+bv[2], v[3]+bv[3]);
      *(u32x2*)&dst[(((int64_t)(bb*HH + h))*SS + s)*DKK + dk0] = w;
    }
  }
}

// v projection: normal layout, out bf16 [b,h,dk,s], 8B stores over consecutive s
__global__ __launch_bounds__(512,2)
void v_wide(const unsigned short* __restrict__ Xv, const unsigned short* __restrict__ bWv,
            const float* __restrict__ bv, unsigned short* __restrict__ vTbuf)
{
  const int m0 = blockIdx.x * 64;
  f32x4 acc[2][10];
  #pragma unroll
  for (int i=0;i<2;i++)
    #pragma unroll
    for (int j=0;j<10;j++){ f32x4 z={0.f,0.f,0.f,0.f}; acc[i][j]=z; }
  wide_gemm<false>(Xv, bWv, m0, acc);

  const int lane = threadIdx.x & 63, wave = threadIdx.x >> 6;
  const int wm = wave>>2, wn = wave&3, l15 = lane&15, g = lane>>4;
  #pragma unroll
  for (int mi=0;mi<2;mi++){
    const int rowb = m0 + wm*32 + mi*16 + g*4;    // 4 consecutive tokens
    const int bb = rowb >> 9, s0 = rowb & 511;
    #pragma unroll
    for (int ni=0;ni<10;ni++){
      const int col = wn*160 + ni*16 + l15;
      const int h = col >> 6, dk = col & 63;
      const float bvv = bv[col];
      f32x4 v = acc[mi][ni];
      u32x2 w;
      w[0] = cvtpk_bf16(v[0]+bvv, v[1]+bvv);
      w[1] = cvtpk_bf16(v[2]+bvv, v[3]+bvv);
      *(u32x2*)&vTbuf[(((int64_t)(bb*HH + h))*DKK + dk)*SS + s0] = w;
    }
  }
}

// s-GEMM + squash fused: out = squash((A*scale) @ RW); bf16 out or final f32 out
__global__ __launch_bounds__(512,2)
void s_kernel(const unsigned short* __restrict__ A, const unsigned short* __restrict__ W,
              float scale, int final_out, unsigned short* __restrict__ bout,
              float* __restrict__ fout)
{
  __shared__ float Ps[64][4];
  const int m0 = blockIdx.x * 64;
  f32x4 acc[2][10];
  #pragma unroll
  for (int i=0;i<2;i++)
    #pragma unroll
    for (int j=0;j<10;j++){ f32x4 z={0.f,0.f,0.f,0.f}; acc[i][j]=z; }
  wide_gemm<true>(A, W, m0, acc);

  const int lane = threadIdx.x & 63, wave = threadIdx.x >> 6;
  const int wm = wave>>2, wn = wave&3, l15 = lane&15, g = lane>>4;

  float part[2] = {0.f, 0.f};
  #pragma unroll
  for (int mi=0;mi<2;mi++)
    #pragma unroll
    for (int ni=0;ni<10;ni++){
      f32x4 v = acc[mi][ni];
      #pragma unroll
      for (int r=0;r<4;r++) v[r] *= scale;
      acc[mi][ni] = v;
      part[mi] += v[0]*v[0] + v[1]*v[1] + v[2]*v[2] + v[3]*v[3];
    }
  #pragma unroll
  for (int mi=0;mi<2;mi++){
    part[mi] += __shfl_xor(part[mi], 16);
    part[mi] += __shfl_xor(part[mi], 32);
  }
  __syncthreads();   // wide_gemm's last barrier already passed; protect Ps reuse
  if (lane < 16){
    Ps[wm*32 + lane][wn]      = part[0];
    Ps[wm*32 + 16 + lane][wn] = part[1];
  }
  __syncthreads();
  #pragma unroll
  for (int mi=0;mi<2;mi++){
    const int t = wm*32 + mi*16 + l15;
    const float sn = Ps[t][0] + Ps[t][1] + Ps[t][2] + Ps[t][3];
    const float sq = (sn/(1.0f+sn)) * rsqrtf(sn + 1e-9f);
    const int token = m0 + t;
    #pragma unroll
    for (int ni=0;ni<10;ni++){
      const int col0 = wn*160 + ni*16 + g*4;
      f32x4 v = acc[mi][ni];
      if (final_out){
        f32x4 o; o[0]=v[0]*sq; o[1]=v[1]*sq; o[2]=v[2]*sq; o[3]=v[3]*sq;
        *(f32x4*)(fout + (int64_t)token*DD + col0) = o;
      } else {
        u32x2 w;
        w[0] = cvtpk_bf16(v[0]*sq, v[1]*sq);
        w[1] = cvtpk_bf16(v[2]*sq, v[3]*sq);
        *(u32x2*)&bout[(int64_t)token*DD + col0] = w;
      }
    }
  }
}

// g-GEMM + route_update fused: g = out @ RW^T-rows; dv[h]=sum x*g per head;
// logits (+)= dv; probs=softmax; xs = x*probs
__global__ __launch_bounds__(512,2)
void g_kernel(const unsigned short* __restrict__ A, const unsigned short* __restrict__ W,
              const unsigned short* __restrict__ x, float* __restrict__ logits,
              unsigned short* __restrict__ xs, int first)
{
  __shared__ float Pd[64][40];
  const int m0 = blockIdx.x * 64;
  f32x4 acc[2][10];
  #pragma unroll
  for (int i=0;i<2;i++)
    #pragma unroll
    for (int j=0;j<10;j++){ f32x4 z={0.f,0.f,0.f,0.f}; acc[i][j]=z; }
  wide_gemm<true>(A, W, m0, acc);

  const int tid = threadIdx.x;
  const int lane = tid & 63, wave = tid >> 6;
  const int wm = wave>>2, wn = wave&3, l15 = lane&15, g = lane>>4;

  float dvp[2][10];
  #pragma unroll
  for (int mi=0;mi<2;mi++){
    const int token = m0 + wm*32 + mi*16 + l15;
    #pragma unroll
    for (int ni=0;ni<10;ni++){
      const int col0 = wn*160 + ni*16 + g*4;
      u16x4 xv = *(const u16x4*)(x + (int64_t)token*DD + col0);
      f32x4 v = acc[mi][ni];
      dvp[mi][ni] = bf2f(xv[0])*v[0] + bf2f(xv[1])*v[1]
                  + bf2f(xv[2])*v[2] + bf2f(xv[3])*v[3];
    }
  }
  #pragma unroll
  for (int mi=0;mi<2;mi++)
    #pragma unroll
    for (int ni=0;ni<10;ni++){
      dvp[mi][ni] += __shfl_xor(dvp[mi][ni], 16);
      dvp[mi][ni] += __shfl_xor(dvp[mi][ni], 32);
    }
  __syncthreads();
  if (lane < 16){
    #pragma unroll
    for (int mi=0;mi<2;mi++)
      #pragma unroll
      for (int ni=0;ni<10;ni++)
        Pd[wm*32 + mi*16 + lane][wn*10 + ni] = dvp[mi][ni];
  }
  __syncthreads();

  const int t = tid >> 3, sub = tid & 7;
  float lg[10];
  #pragma unroll
  for (int h=0;h<10;h++){
    const float dv = Pd[t][4*h] + Pd[t][4*h+1] + Pd[t][4*h+2] + Pd[t][4*h+3];
    lg[h] = (first ? 0.0f : logits[(m0 + t)*10 + h]) + dv;
  }
  if (sub == 0){
    #pragma unroll
    for (int h=0;h<10;h++) logits[(m0 + t)*10 + h] = lg[h];
  }
  float mx = lg[0];
  #pragma unroll
  for (int h=1;h<10;h++) mx = fmaxf(mx, lg[h]);
  float se = 0.f;
  #pragma unroll
  for (int h=0;h<10;h++){ lg[h] = __expf(lg[h]-mx); se += lg[h]; }
  const float inv = 1.0f/se;
  #pragma unroll
  for (int hh=0;hh<10;hh++){
    const float p = lg[hh]*inv;
    const int col0 = hh*64 + sub*8;
    const unsigned short* xr = x  + (int64_t)(m0 + t)*DD + col0;
    unsigned short*       xo = xs + (int64_t)(m0 + t)*DD + col0;
    u16x4 xa = *(const u16x4*)xr;
    u16x4 xb = *(const u16x4*)(xr + 4);
    u32x2 wa, wb;
    wa[0] = cvtpk_bf16(bf2f(xa[0])*p, bf2f(xa[1])*p);
    wa[1] = cvtpk_bf16(bf2f(xa[2])*p, bf2f(xa[3])*p);
    wb[0] = cvtpk_bf16(bf2f(xb[0])*p, bf2f(xb[1])*p);
    wb[1] = cvtpk_bf16(bf2f(xb[2])*p, bf2f(xb[3])*p);
    *(u32x2*)xo       = wa;
    *(u32x2*)(xo + 4) = wb;
  }
}

// ---------------- attention (unchanged) ----------------
__global__ __launch_bounds__(256)
void attn_kernel(const unsigned short* __restrict__ qb, const unsigned short* __restrict__ kb,
                 const unsigned short* __restrict__ vT, const unsigned short* __restrict__ biasT,
                 unsigned short* __restrict__ xout)
{
  __shared__ unsigned short SH[20480];   // 40KB: K 2x8KB | V 2x8KB | P 4x2KB
  unsigned short* Kl = SH;               // [2][4096]
  unsigned short* Vl = SH + 8192;        // [2][4096]
  char* Pall = (char*)(SH + 16384);

  const int tid  = threadIdx.x;
  const int lane = tid & 63;
  const int wave = tid >> 6;
  const int l15  = lane & 15;
  const int g    = lane >> 4;

  const int qt = blockIdx.x;   // 0..7
  const int h  = blockIdx.y;   // 0..9
  const int b  = blockIdx.z;   // 0..31
  const int bh = b*HH + h;

  const unsigned short* Q  = qb + (int64_t)bh*SS*DKK;
  const unsigned short* K  = kb + (int64_t)bh*SS*DKK;
  const unsigned short* V  = vT + (int64_t)bh*DKK*SS;
  const unsigned short* Bt = biasT + (int64_t)((b*32 + qt*4 + wave)*32)*256
                           + l15*16 + g*4;

  const int q0 = qt*64 + wave*16;
  char* Pb = Pall + wave*2048;           // 16 rows x 128B

  const int srow8 = lane >> 3;
  const int sunit = (lane & 7) ^ (srow8 & 7);

  bf16x8 qf[2];
  #pragma unroll
  for (int ks=0; ks<2; ks++)
    qf[ks] = *(const bf16x8*)(Q + (q0 + l15)*DKK + ks*32 + g*8);

  auto stage = [&](int c, int buf){
    #pragma unroll
    for (int c2=0;c2<2;c2++){
      const int i = wave*2 + c2;                      // 0..7 across waves
      gload_lds16(K + (int64_t)(c*64 + i*8 + srow8)*DKK + sunit*8,
                  Kl + buf*4096 + i*512);
      gload_lds16(V + (int64_t)(i*8 + srow8)*SS + c*64 + sunit*8,
                  Vl + buf*4096 + i*512);
    }
  };

  float lsum = 0.f;
  f32x4 oacc[4];
  #pragma unroll
  for (int n=0;n<4;n++){ f32x4 z={0.f,0.f,0.f,0.f}; oacc[n]=z; }

  u16x4 bvc[4], bvn[4];
  #pragma unroll
  for (int j=0;j<4;j++) bvc[j] = *(const u16x4*)(Bt + j*256);

  stage(0, 0);
  for (int c = 0; c < 8; c++){
    const int buf = c & 1;
    __syncthreads();                     // stage(c) landed; buf^1 readers done
    if (c < 7){
      stage(c+1, buf^1);
      #pragma unroll
      for (int j=0;j<4;j++) bvn[j] = *(const u16x4*)(Bt + ((c+1)*4 + j)*256);
    }

    f32x4 sc[4];
    #pragma unroll
    for (int j=0;j<4;j++){ f32x4 z={0.f,0.f,0.f,0.f}; sc[j]=z; }
    #pragma unroll
    for (int ks=0; ks<2; ks++){
      #pragma unroll
      for (int j=0;j<4;j++){
        bf16x8 kf = *(const bf16x8*)((char*)(Kl + buf*4096)
                     + (j*16 + l15)*128 + (((ks*4+g) ^ (l15&7))*16));
        sc[j] = __builtin_amdgcn_mfma_f32_16x16x32_bf16(kf, qf[ks], sc[j], 0,0,0);
      }
    }
    #pragma unroll
    for (int j=0;j<4;j++){
      float p[4];
      #pragma unroll
      for (int r=0;r<4;r++){
        float s = __builtin_fmaf(sc[j][r], 0.125f, bf2f(bvc[j][r]));
        p[r] = __expf(s - 8.0f);
        lsum += p[r];
      }
      unsigned int w0 = cvtpk_bf16(p[0], p[1]);
      unsigned int w1 = cvtpk_bf16(p[2], p[3]);
      const int kk = j*16 + g*4;
      const int sw = (kk >> 3) ^ (l15 & 7);
      u32x2 w; w[0]=w0; w[1]=w1;
      *(u32x2*)(Pb + l15*128 + sw*16 + (kk&7)*2) = w;
    }
    #pragma unroll
    for (int kt=0; kt<2; kt++){
      bf16x8 pf = *(const bf16x8*)(Pb + l15*128 + (((kt*4+g) ^ (l15&7))*16));
      #pragma unroll
      for (int n=0;n<4;n++){
        bf16x8 vf = *(const bf16x8*)((char*)(Vl + buf*4096)
                     + (n*16 + l15)*128 + (((kt*4+g) ^ (l15&7))*16));
        oacc[n] = __builtin_amdgcn_mfma_f32_16x16x32_bf16(pf, vf, oacc[n], 0,0,0);
      }
    }
    #pragma unroll
    for (int j=0;j<4;j++) bvc[j] = bvn[j];
  }

  lsum += __shfl_xor(lsum, 16);
  lsum += __shfl_xor(lsum, 32);
  const float inv = 1.0f / lsum;          // valid for q=l15
  float invr[4];
  #pragma unroll
  for (int r=0;r<4;r++) invr[r] = __shfl(inv, g*4 + r);

  #pragma unroll
  for (int n=0;n<4;n++){
    const int dk = n*16 + l15;
    #pragma unroll
    for (int r=0;r<4;r++){
      const int qrow = q0 + g*4 + r;
      const int ntok = b*SS + qrow;
      xout[(int64_t)ntok*DD + h*DKK + dk] = f2bf(oacc[n][r] * invr[r]);
    }
  }
}

// ---------------- launch ----------------
extern "C" void kernel_launch(void* const* d_in, const int* in_sizes, int n_in,
                              void* d_out, int out_size, void* d_ws, size_t ws_size,
                              hipStream_t stream)
{
  (void)in_sizes; (void)n_in; (void)out_size; (void)ws_size;
  const float* q    = (const float*)d_in[0];
  const float* k    = (const float*)d_in[1];
  const float* v    = (const float*)d_in[2];
  const int*   mask = (const int*)d_in[3];
  const float* adj  = (const float*)d_in[4];
  const int*   layer= (const int*)d_in[5];
  const float* Wq   = (const float*)d_in[6];
  const float* bq   = (const float*)d_in[7];
  const float* Wk   = (const float*)d_in[8];
  const float* bk   = (const float*)d_in[9];
  const float* Wv   = (const float*)d_in[10];
  const float* bv   = (const float*)d_in[11];
  const float* rw   = (const float*)d_in[12];

  char* ws = (char*)d_ws;
  size_t off = 0;
  auto alloc = [&](size_t sz)->char*{ char* p = ws + off; off += (sz + 255) & ~(size_t)255; return p; };
  const size_t SZX = (size_t)NTOK*DD*2;
  unsigned short* Xq    = (unsigned short*)alloc(SZX);
  unsigned short* Xk    = (unsigned short*)alloc(SZX);
  unsigned short* Xv    = (unsigned short*)alloc(SZX);
  unsigned short* bWq   = (unsigned short*)alloc((size_t)DD*DD*2);
  unsigned short* bWk   = (unsigned short*)alloc((size_t)DD*DD*2);
  unsigned short* bWv   = (unsigned short*)alloc((size_t)DD*DD*2);
  unsigned short* bRW   = (unsigned short*)alloc((size_t)DD*DD*2);
  unsigned short* bRWT  = (unsigned short*)alloc((size_t)DD*DD*2);
  unsigned short* qbuf  = (unsigned short*)alloc(SZX);
  unsigned short* kbuf  = (unsigned short*)alloc(SZX);
  unsigned short* vTbuf = (unsigned short*)alloc(SZX);
  unsigned short* biasb = (unsigned short*)alloc((size_t)BB*SS*SS*2);
  unsigned short* xsb   = (unsigned short*)alloc(SZX);
  float*          logit = (float*)alloc((size_t)NTOK*10*4);
  // aliases (provably dead at reuse time, stream-ordered):
  unsigned short* xout  = Xq;    // Xq dead after q-projection
  unsigned short* outit = Xk;    // Xk dead after k-projection

  convert_qkv<<<2048,256,0,stream>>>(q,k,v,Xq,Xk,Xv);
  convert_w<<<1600,256,0,stream>>>(Wq,Wk,Wv,rw,bWq,bWk,bWv,bRW,bRWT);
  bias_kernel<<<2048,256,0,stream>>>(mask,adj,layer,biasb);

  dim3 gqk(NTOK/64, 2);
  qk_wide<<<gqk,512,0,stream>>>(Xq,Xk,bWq,bWk,bq,bk,qbuf,kbuf);
  v_wide<<<NTOK/64,512,0,stream>>>(Xv,bWv,bv,vTbuf);

  dim3 ga(8, HH, BB);
  attn_kernel<<<ga,256,0,stream>>>(qbuf,kbuf,vTbuf,biasb,xout);

  // routing: it0 (uniform probs 1/10 folded into scale)
  s_kernel<<<NTOK/64,512,0,stream>>>(xout,bRWT,0.1f,0,outit,nullptr);
  g_kernel<<<NTOK/64,512,0,stream>>>(outit,bRW,xout,logit,xsb,1);
  // it1
  s_kernel<<<NTOK/64,512,0,stream>>>(xsb,bRWT,1.0f,0,outit,nullptr);
  g_kernel<<<NTOK/64,512,0,stream>>>(outit,bRW,xout,logit,xsb,0);
  // it2 (final)
  s_kernel<<<NTOK/64,512,0,stream>>>(xsb,bRWT,1.0f,1,nullptr,(float*)d_out);
}

// Round 8
// 348.367 us; speedup vs baseline: 1.1715x; 1.1715x over previous
//
#include <hip/hip_runtime.h>
#include <stdint.h>

#define BB 32
#define SS 512
#define DD 640
#define HH 10
#define DKK 64
#define NTOK (BB*SS)   // 16384

using f32x4  = __attribute__((ext_vector_type(4))) float;
using bf16x8 = __attribute__((ext_vector_type(8))) __bf16;
using u32x4  = __attribute__((ext_vector_type(4))) unsigned int;
using u32x2  = __attribute__((ext_vector_type(2))) unsigned int;
using u16x4  = __attribute__((ext_vector_type(4))) unsigned short;
using i32x4  = __attribute__((ext_vector_type(4))) int;

__device__ inline unsigned short f2bf(float f){
  union { float f; unsigned int u; } v; v.f=f;
  unsigned int u=v.u;
  u += 0x7FFFu + ((u>>16)&1u);
  return (unsigned short)(u>>16);
}
__device__ inline float bf2f(unsigned short s){
  union { unsigned int u; float f; } v; v.u = ((unsigned int)s)<<16;
  return v.f;
}
__device__ inline unsigned int cvtpk_bf16(float lo, float hi){
  unsigned int r;
  asm volatile("v_cvt_pk_bf16_f32 %0, %1, %2" : "=v"(r) : "v"(lo), "v"(hi));
  return r;
}
__device__ inline void gload_lds16(const unsigned short* g, unsigned short* l){
  __builtin_amdgcn_global_load_lds(
      (const __attribute__((address_space(1))) unsigned int*)g,
      (__attribute__((address_space(3))) unsigned int*)l, 16, 0, 0);
}

// ---------------- conversions ----------------
__global__ void convert_qkv(const float* __restrict__ q, const float* __restrict__ k,
                            const float* __restrict__ v,
                            unsigned short* __restrict__ xq, unsigned short* __restrict__ xk,
                            unsigned short* __restrict__ xv){
  int i = blockIdx.x*blockDim.x + threadIdx.x;
  const int n4 = (NTOK*DD)/4;
  for (; i < n4; i += gridDim.x*blockDim.x){
    f32x4 a = ((const f32x4*)q)[i];
    f32x4 b = ((const f32x4*)k)[i];
    f32x4 c = ((const f32x4*)v)[i];
    u16x4 ra, rb, rc;
    #pragma unroll
    for (int j=0;j<4;j++){ ra[j]=f2bf(a[j]); rb[j]=f2bf(b[j]); rc[j]=f2bf(c[j]); }
    ((u16x4*)xq)[i]=ra; ((u16x4*)xk)[i]=rb; ((u16x4*)xv)[i]=rc;
  }
}

__global__ void convert_w(const float* __restrict__ wq, const float* __restrict__ wk,
                          const float* __restrict__ wv, const float* __restrict__ rw,
                          unsigned short* __restrict__ bwq, unsigned short* __restrict__ bwk,
                          unsigned short* __restrict__ bwv, unsigned short* __restrict__ brw,
                          unsigned short* __restrict__ brwt){
  int i = blockIdx.x*blockDim.x + threadIdx.x;
  if (i < DD*DD){
    bwq[i]=f2bf(wq[i]); bwk[i]=f2bf(wk[i]); bwv[i]=f2bf(wv[i]);
    unsigned short r = f2bf(rw[i]);
    brw[i]=r;
    int ri = i / DD, o = i % DD;
    brwt[o*DD + ri] = r;
  }
}

// bias in 16x16-tile layout: biasT[((b*32 + q>>4)*32 + k>>4)*256 + (q&15)*16 + (k&15)]
__global__ void bias_kernel(const int* __restrict__ mask, const float* __restrict__ adj,
                            const int* __restrict__ layer, unsigned short* __restrict__ biasT){
  float sc = 1.0f/(float)(layer[0]+1);
  int i = blockIdx.x*blockDim.x + threadIdx.x;
  const int n4 = (BB*SS*SS)/4;
  for (; i < n4; i += gridDim.x*blockDim.x){
    i32x4 m = ((const i32x4*)mask)[i];
    f32x4 a = ((const f32x4*)adj)[i];
    u16x4 r;
    #pragma unroll
    for (int j=0;j<4;j++) r[j] = m[j] ? f2bf(a[j]*sc) : f2bf(-1e9f);
    const int e  = i*4;
    const int bb = e >> 18;
    const int qq = (e >> 9) & 511;
    const int kk = e & 511;
    const int idx = (((bb*32 + (qq>>4))*32 + (kk>>4))<<8) + ((qq&15)<<4) + (kk&15);
    *(u16x4*)(biasT + idx) = r;
  }
}

// ---------------- GEMM bodies (128x128, BK=32, 256 thr, dbuf) ----------------
// Swizzle pair (R7-verified, conflicts=0): stored octet u of row r holds logical
// octet u ^ ((r>>1)&3); staged via pre-swizzled global source, read with fro.
#define BM 128
#define BN 128
#define BK 32

template<typename EPI>
__device__ inline void gemm_body(const unsigned short* __restrict__ A,
                                 const unsigned short* __restrict__ W,
                                 int m0, int n0, EPI&& epi)
{
  __shared__ unsigned short As[2][BM*BK];
  __shared__ unsigned short Ws[2][BN*BK];
  const int tid  = threadIdx.x;
  const int lane = tid & 63;
  const int wave = tid >> 6;
  const int wr   = (wave >> 1) * 64;
  const int wc   = (wave & 1) * 64;
  const int l15  = lane & 15;
  const int g    = lane >> 4;

  f32x4 acc[4][4];
  #pragma unroll
  for (int i=0;i<4;i++)
    #pragma unroll
    for (int j=0;j<4;j++){ f32x4 z = {0.f,0.f,0.f,0.f}; acc[i][j]=z; }

  const int srow  = (lane >> 2);
  const int sunit = (lane & 3) ^ ((lane >> 3) & 3);   // pre-swizzled source octet
  const unsigned short* Ag0 = A + (int64_t)(m0 + wave*32 + srow)*DD + sunit*8;
  const unsigned short* Ag1 = A + (int64_t)(m0 + wave*32 + 16 + srow)*DD + sunit*8;
  const unsigned short* Wg0 = W + (int64_t)(n0 + wave*32 + srow)*DD + sunit*8;
  const unsigned short* Wg1 = W + (int64_t)(n0 + wave*32 + 16 + srow)*DD + sunit*8;

  auto stage = [&](int buf, int k0){
    gload_lds16(Ag0 + k0, As[buf] + wave*1024);
    gload_lds16(Ag1 + k0, As[buf] + wave*1024 + 512);
    gload_lds16(Wg0 + k0, Ws[buf] + wave*1024);
    gload_lds16(Wg1 + k0, Ws[buf] + wave*1024 + 512);
  };

  const int fro = (g ^ ((l15 >> 1) & 3)) * 8;         // swizzled read offset

  stage(0, 0);
  int it = 0;
  for (int k0 = 0; k0 < DD; k0 += BK, it++){
    const int buf = it & 1;
    __syncthreads();               // stage(buf) landed; prior readers of buf^1 done
    if (k0 + BK < DD) stage(buf^1, k0 + BK);
    bf16x8 af[4], wf[4];
    #pragma unroll
    for (int m=0;m<4;m++) af[m] = *(const bf16x8*)&As[buf][(wr + m*16 + l15)*BK + fro];
    #pragma unroll
    for (int n=0;n<4;n++) wf[n] = *(const bf16x8*)&Ws[buf][(wc + n*16 + l15)*BK + fro];
    #pragma unroll
    for (int m=0;m<4;m++)
      #pragma unroll
      for (int n=0;n<4;n++)
        acc[m][n] = __builtin_amdgcn_mfma_f32_16x16x32_bf16(af[m], wf[n], acc[m][n], 0,0,0);
  }

  #pragma unroll
  for (int m=0;m<4;m++){
    const int rowbase = m0 + wr + m*16 + g*4;
    #pragma unroll
    for (int n=0;n<4;n++){
      const int col = n0 + wc + n*16 + l15;
      #pragma unroll
      for (int r=0;r<4;r++)
        epi(rowbase + r, col, acc[m][n][r]);
    }
  }
}

// merged QKV projection: grid (128, 15); y/5 selects {q,k,v}, y%5 selects n-tile
__global__ __launch_bounds__(256)
void qkv_gemm(const unsigned short* __restrict__ Xq, const unsigned short* __restrict__ Xk,
              const unsigned short* __restrict__ Xv,
              const unsigned short* __restrict__ bWq, const unsigned short* __restrict__ bWk,
              const unsigned short* __restrict__ bWv,
              const float* __restrict__ bq, const float* __restrict__ bk,
              const float* __restrict__ bv,
              unsigned short* __restrict__ qbuf, unsigned short* __restrict__ kbuf,
              unsigned short* __restrict__ vTbuf)
{
  const int y   = blockIdx.y;
  const int sel = y / 5;
  const int n0  = (y % 5) * BN;
  const int m0  = blockIdx.x * BM;
  const unsigned short* A = sel==0 ? Xq  : sel==1 ? Xk  : Xv;
  const unsigned short* W = sel==0 ? bWq : sel==1 ? bWk : bWv;
  const float*          bb= sel==0 ? bq  : sel==1 ? bk  : bv;
  unsigned short* outp    = sel==0 ? qbuf : kbuf;

  gemm_body(A, W, m0, n0, [&](int row, int col, float v){
    float val = v + bb[col];
    int b=row>>9, s=row&511, h=col>>6, dk=col&63;
    if (sel < 2)
      outp[(((int64_t)(b*HH + h))*SS + s)*DKK + dk] = f2bf(val);
    else
      vTbuf[(((int64_t)(b*HH + h))*DKK + dk)*SS + s] = f2bf(val);
  });
}

// routing GEMM: C = (A @ W^T) * scale, bf16 out [n,j]
__global__ __launch_bounds__(256)
void gemm_nt(const unsigned short* __restrict__ A, const unsigned short* __restrict__ W,
             unsigned short* __restrict__ outp, float scale)
{
  gemm_body(A, W, blockIdx.x*BM, blockIdx.y*BN, [&](int row, int col, float v){
    outp[(int64_t)row*DD + col] = f2bf(v*scale);
  });
}

// ---------------- attention ----------------
// 1D grid 2560 with bijective XCD-chunk swizzle (2560%8==0): wgid=(orig&7)*320+orig>>3.
// h-fastest decode -> each XCD owns 4 batches' bias slice (2MB, L2-resident).
__global__ __launch_bounds__(256)
void attn_kernel(const unsigned short* __restrict__ qb, const unsigned short* __restrict__ kb,
                 const unsigned short* __restrict__ vT, const unsigned short* __restrict__ biasT,
                 unsigned short* __restrict__ xout)
{
  __shared__ unsigned short SH[20480];   // 40KB: K 2x8KB | V 2x8KB | P 4x2KB
  unsigned short* Kl = SH;               // [2][4096]
  unsigned short* Vl = SH + 8192;        // [2][4096]
  char* Pall = (char*)(SH + 16384);

  const int tid  = threadIdx.x;
  const int lane = tid & 63;
  const int wave = tid >> 6;
  const int l15  = lane & 15;
  const int g    = lane >> 4;

  const int orig = blockIdx.x;
  const int wgid = (orig & 7)*320 + (orig >> 3);   // XCD-chunk swizzle
  const int h  = wgid % 10;
  const int qt = (wgid / 10) & 7;
  const int b  = wgid / 80;
  const int bh = b*HH + h;

  const unsigned short* Q  = qb + (int64_t)bh*SS*DKK;
  const unsigned short* K  = kb + (int64_t)bh*SS*DKK;
  const unsigned short* V  = vT + (int64_t)bh*DKK*SS;
  const unsigned short* Bt = biasT + (int64_t)((b*32 + qt*4 + wave)*32)*256
                           + l15*16 + g*4;

  const int q0 = qt*64 + wave*16;
  char* Pb = Pall + wave*2048;           // 16 rows x 128B

  const int srow8 = lane >> 3;
  const int sunit = (lane & 7) ^ (srow8 & 7);

  bf16x8 qf[2];
  #pragma unroll
  for (int ks=0; ks<2; ks++)
    qf[ks] = *(const bf16x8*)(Q + (q0 + l15)*DKK + ks*32 + g*8);

  auto stage = [&](int c, int buf){
    #pragma unroll
    for (int c2=0;c2<2;c2++){
      const int i = wave*2 + c2;                      // 0..7 across waves
      gload_lds16(K + (int64_t)(c*64 + i*8 + srow8)*DKK + sunit*8,
                  Kl + buf*4096 + i*512);
      gload_lds16(V + (int64_t)(i*8 + srow8)*SS + c*64 + sunit*8,
                  Vl + buf*4096 + i*512);
    }
  };

  float lsum = 0.f;
  f32x4 oacc[4];
  #pragma unroll
  for (int n=0;n<4;n++){ f32x4 z={0.f,0.f,0.f,0.f}; oacc[n]=z; }

  u16x4 bvc[4], bvn[4];
  #pragma unroll
  for (int j=0;j<4;j++) bvc[j] = *(const u16x4*)(Bt + j*256);

  stage(0, 0);
  for (int c = 0; c < 8; c++){
    const int buf = c & 1;
    __syncthreads();                     // stage(c) landed; buf^1 readers done
    if (c < 7){
      stage(c+1, buf^1);
      #pragma unroll
      for (int j=0;j<4;j++) bvn[j] = *(const u16x4*)(Bt + ((c+1)*4 + j)*256);
    }

    f32x4 sc[4];
    #pragma unroll
    for (int j=0;j<4;j++){ f32x4 z={0.f,0.f,0.f,0.f}; sc[j]=z; }
    #pragma unroll
    for (int ks=0; ks<2; ks++){
      #pragma unroll
      for (int j=0;j<4;j++){
        bf16x8 kf = *(const bf16x8*)((char*)(Kl + buf*4096)
                     + (j*16 + l15)*128 + (((ks*4+g) ^ (l15&7))*16));
        sc[j] = __builtin_amdgcn_mfma_f32_16x16x32_bf16(kf, qf[ks], sc[j], 0,0,0);
      }
    }
    #pragma unroll
    for (int j=0;j<4;j++){
      float p[4];
      #pragma unroll
      for (int r=0;r<4;r++){
        float s = __builtin_fmaf(sc[j][r], 0.125f, bf2f(bvc[j][r]));
        p[r] = __expf(s - 8.0f);
        lsum += p[r];
      }
      unsigned int w0 = cvtpk_bf16(p[0], p[1]);
      unsigned int w1 = cvtpk_bf16(p[2], p[3]);
      const int kk = j*16 + g*4;
      const int sw = (kk >> 3) ^ (l15 & 7);
      u32x2 w; w[0]=w0; w[1]=w1;
      *(u32x2*)(Pb + l15*128 + sw*16 + (kk&7)*2) = w;
    }
    #pragma unroll
    for (int kt=0; kt<2; kt++){
      bf16x8 pf = *(const bf16x8*)(Pb + l15*128 + (((kt*4+g) ^ (l15&7))*16));
      #pragma unroll
      for (int n=0;n<4;n++){
        bf16x8 vf = *(const bf16x8*)((char*)(Vl + buf*4096)
                     + (n*16 + l15)*128 + (((kt*4+g) ^ (l15&7))*16));
        oacc[n] = __builtin_amdgcn_mfma_f32_16x16x32_bf16(pf, vf, oacc[n], 0,0,0);
      }
    }
    #pragma unroll
    for (int j=0;j<4;j++) bvc[j] = bvn[j];
  }

  lsum += __shfl_xor(lsum, 16);
  lsum += __shfl_xor(lsum, 32);
  const float inv = 1.0f / lsum;          // valid for q=l15
  float invr[4];
  #pragma unroll
  for (int r=0;r<4;r++) invr[r] = __shfl(inv, g*4 + r);

  #pragma unroll
  for (int n=0;n<4;n++){
    const int dk = n*16 + l15;
    #pragma unroll
    for (int r=0;r<4;r++){
      const int qrow = q0 + g*4 + r;
      const int ntok = b*SS + qrow;
      xout[(int64_t)ntok*DD + h*DKK + dk] = f2bf(oacc[n][r] * invr[r]);
    }
  }
}

// ---------------- routing elementwise ----------------
__global__ void squash_kernel(const unsigned short* __restrict__ sin,
                              unsigned short* __restrict__ bout,
                              float* __restrict__ fout, int final_out)
{
  const int widx = (blockIdx.x*blockDim.x + threadIdx.x) >> 6;
  const int lane = threadIdx.x & 63;
  if (widx >= NTOK) return;
  const unsigned short* row = sin + (int64_t)widx*DD;
  float v[10]; float sn = 0.f;
  #pragma unroll
  for (int i=0;i<10;i++){ v[i] = bf2f(row[i*64 + lane]); sn += v[i]*v[i]; }
  #pragma unroll
  for (int off=1; off<64; off<<=1) sn += __shfl_xor(sn, off);
  const float sc = (sn/(1.0f+sn)) * rsqrtf(sn + 1e-9f);
  if (final_out){
    float* o = fout + (int64_t)widx*DD;
    #pragma unroll
    for (int i=0;i<10;i++) o[i*64+lane] = v[i]*sc;
  } else {
    unsigned short* o = bout + (int64_t)widx*DD;
    #pragma unroll
    for (int i=0;i<10;i++) o[i*64+lane] = f2bf(v[i]*sc);
  }
}

__global__ void route_update(const unsigned short* __restrict__ x,
                             const unsigned short* __restrict__ gbuf,
                             float* __restrict__ logits,
                             unsigned short* __restrict__ xs, int first)
{
  const int widx = (blockIdx.x*blockDim.x + threadIdx.x) >> 6;
  const int lane = threadIdx.x & 63;
  if (widx >= NTOK) return;
  const unsigned short* xr = x + (int64_t)widx*DD;
  const unsigned short* gr = gbuf + (int64_t)widx*DD;
  float xv[10], dv[10];
  #pragma unroll
  for (int i=0;i<10;i++){
    xv[i] = bf2f(xr[i*64+lane]);
    dv[i] = xv[i]*bf2f(gr[i*64+lane]);
  }
  #pragma unroll
  for (int i=0;i<10;i++){
    float v = dv[i];
    #pragma unroll
    for (int off=1; off<64; off<<=1) v += __shfl_xor(v, off);
    dv[i] = v;
  }
  float* lrow = logits + widx*10;
  float lg[10];
  #pragma unroll
  for (int i=0;i<10;i++) lg[i] = first ? dv[i] : (lrow[i] + dv[i]);
  #pragma unroll
  for (int i=0;i<10;i++) if (lane == i) lrow[i] = lg[i];
  float mx = lg[0];
  #pragma unroll
  for (int i=1;i<10;i++) mx = fmaxf(mx, lg[i]);
  float se = 0.f;
  #pragma unroll
  for (int i=0;i<10;i++){ lg[i] = __expf(lg[i]-mx); se += lg[i]; }
  const float inv = 1.0f/se;
  unsigned short* xo = xs + (int64_t)widx*DD;
  #pragma unroll
  for (int i=0;i<10;i++) xo[i*64+lane] = f2bf(xv[i]*lg[i]*inv);
}

// ---------------- launch ----------------
extern "C" void kernel_launch(void* const* d_in, const int* in_sizes, int n_in,
                              void* d_out, int out_size, void* d_ws, size_t ws_size,
                              hipStream_t stream)
{
  (void)in_sizes; (void)n_in; (void)out_size; (void)ws_size;
  const float* q    = (const float*)d_in[0];
  const float* k    = (const float*)d_in[1];
  const float* v    = (const float*)d_in[2];
  const int*   mask = (const int*)d_in[3];
  const float* adj  = (const float*)d_in[4];
  const int*   layer= (const int*)d_in[5];
  const float* Wq   = (const float*)d_in[6];
  const float* bq   = (const float*)d_in[7];
  const float* Wk   = (const float*)d_in[8];
  const float* bk   = (const float*)d_in[9];
  const float* Wv   = (const float*)d_in[10];
  const float* bv   = (const float*)d_in[11];
  const float* rw   = (const float*)d_in[12];

  char* ws = (char*)d_ws;
  size_t off = 0;
  auto alloc = [&](size_t sz)->char*{ char* p = ws + off; off += (sz + 255) & ~(size_t)255; return p; };
  const size_t SZX = (size_t)NTOK*DD*2;
  unsigned short* Xq    = (unsigned short*)alloc(SZX);
  unsigned short* Xk    = (unsigned short*)alloc(SZX);
  unsigned short* Xv    = (unsigned short*)alloc(SZX);
  unsigned short* bWq   = (unsigned short*)alloc((size_t)DD*DD*2);
  unsigned short* bWk   = (unsigned short*)alloc((size_t)DD*DD*2);
  unsigned short* bWv   = (unsigned short*)alloc((size_t)DD*DD*2);
  unsigned short* bRW   = (unsigned short*)alloc((size_t)DD*DD*2);
  unsigned short* bRWT  = (unsigned short*)alloc((size_t)DD*DD*2);
  unsigned short* qbuf  = (unsigned short*)alloc(SZX);
  unsigned short* kbuf  = (unsigned short*)alloc(SZX);
  unsigned short* vTbuf = (unsigned short*)alloc(SZX);
  unsigned short* biasb = (unsigned short*)alloc((size_t)BB*SS*SS*2);
  unsigned short* xsb   = (unsigned short*)alloc(SZX);
  float*          logit = (float*)alloc((size_t)NTOK*10*4);
  // aliases (provably dead at reuse time, stream-ordered):
  unsigned short* xout  = Xq;    // Xq dead after q-projection
  unsigned short* outit = Xk;    // Xk dead after k-projection
  unsigned short* gbuf  = Xv;    // Xv dead after v-projection
  unsigned short* sbuf  = qbuf;  // qbuf dead after attention

  convert_qkv<<<2048,256,0,stream>>>(q,k,v,Xq,Xk,Xv);
  convert_w<<<1600,256,0,stream>>>(Wq,Wk,Wv,rw,bWq,bWk,bWv,bRW,bRWT);
  bias_kernel<<<2048,256,0,stream>>>(mask,adj,layer,biasb);

  dim3 gq(NTOK/BM, 15);
  qkv_gemm<<<gq,256,0,stream>>>(Xq,Xk,Xv,bWq,bWk,bWv,bq,bk,bv,qbuf,kbuf,vTbuf);

  attn_kernel<<<2560,256,0,stream>>>(qbuf,kbuf,vTbuf,biasb,xout);

  dim3 gg(NTOK/BM, DD/BN);
  // routing: it0 (uniform probs 1/10 folded into scale)
  gemm_nt<<<gg,256,0,stream>>>(xout,bRWT,sbuf,0.1f);
  squash_kernel<<<4096,256,0,stream>>>(sbuf,outit,nullptr,0);
  gemm_nt<<<gg,256,0,stream>>>(outit,bRW,gbuf,1.0f);
  route_update<<<4096,256,0,stream>>>(xout,gbuf,logit,xsb,1);
  // it1
  gemm_nt<<<gg,256,0,stream>>>(xsb,bRWT,sbuf,1.0f);
  squash_kernel<<<4096,256,0,stream>>>(sbuf,outit,nullptr,0);
  gemm_nt<<<gg,256,0,stream>>>(outit,bRW,gbuf,1.0f);
  route_update<<<4096,256,0,stream>>>(xout,gbuf,logit,xsb,0);
  // it2 (final)
  gemm_nt<<<gg,256,0,stream>>>(xsb,bRWT,sbuf,1.0f);
  squash_kernel<<<4096,256,0,stream>>>(sbuf,nullptr,(float*)d_out,1);
}

// Round 9
// 325.069 us; speedup vs baseline: 1.2555x; 1.0717x over previous
//
#include <hip/hip_runtime.h>
#include <stdint.h>

#define BB 32
#define SS 512
#define DD 640
#define HH 10
#define DKK 64
#define NTOK (BB*SS)   // 16384

using f32x4  = __attribute__((ext_vector_type(4))) float;
using bf16x8 = __attribute__((ext_vector_type(8))) __bf16;
using u32x4  = __attribute__((ext_vector_type(4))) unsigned int;
using u32x2  = __attribute__((ext_vector_type(2))) unsigned int;
using u16x4  = __attribute__((ext_vector_type(4))) unsigned short;
using i32x4  = __attribute__((ext_vector_type(4))) int;

__device__ inline unsigned short f2bf(float f){
  union { float f; unsigned int u; } v; v.f=f;
  unsigned int u=v.u;
  u += 0x7FFFu + ((u>>16)&1u);
  return (unsigned short)(u>>16);
}
__device__ inline float bf2f(unsigned short s){
  union { unsigned int u; float f; } v; v.u = ((unsigned int)s)<<16;
  return v.f;
}
__device__ inline unsigned int cvtpk_bf16(float lo, float hi){
  unsigned int r;
  asm volatile("v_cvt_pk_bf16_f32 %0, %1, %2" : "=v"(r) : "v"(lo), "v"(hi));
  return r;
}
__device__ inline void gload_lds16(const unsigned short* g, unsigned short* l){
  __builtin_amdgcn_global_load_lds(
      (const __attribute__((address_space(1))) unsigned int*)g,
      (__attribute__((address_space(3))) unsigned int*)l, 16, 0, 0);
}

// ---------------- conversions ----------------
__global__ void convert_qkv(const float* __restrict__ q, const float* __restrict__ k,
                            const float* __restrict__ v,
                            unsigned short* __restrict__ xq, unsigned short* __restrict__ xk,
                            unsigned short* __restrict__ xv){
  int i = blockIdx.x*blockDim.x + threadIdx.x;
  const int n4 = (NTOK*DD)/4;
  for (; i < n4; i += gridDim.x*blockDim.x){
    f32x4 a = ((const f32x4*)q)[i];
    f32x4 b = ((const f32x4*)k)[i];
    f32x4 c = ((const f32x4*)v)[i];
    u16x4 ra, rb, rc;
    #pragma unroll
    for (int j=0;j<4;j++){ ra[j]=f2bf(a[j]); rb[j]=f2bf(b[j]); rc[j]=f2bf(c[j]); }
    ((u16x4*)xq)[i]=ra; ((u16x4*)xk)[i]=rb; ((u16x4*)xv)[i]=rc;
  }
}

__global__ void convert_w(const float* __restrict__ wq, const float* __restrict__ wk,
                          const float* __restrict__ wv, const float* __restrict__ rw,
                          unsigned short* __restrict__ bwq, unsigned short* __restrict__ bwk,
                          unsigned short* __restrict__ bwv, unsigned short* __restrict__ brwt){
  int i = blockIdx.x*blockDim.x + threadIdx.x;
  if (i < DD*DD){
    bwq[i]=f2bf(wq[i]); bwk[i]=f2bf(wk[i]); bwv[i]=f2bf(wv[i]);
    unsigned short r = f2bf(rw[i]);
    int ri = i / DD, o = i % DD;
    brwt[o*DD + ri] = r;
  }
}

// bias in 16x16-tile layout: biasT[((b*32 + q>>4)*32 + k>>4)*256 + (q&15)*16 + (k&15)]
__global__ void bias_kernel(const int* __restrict__ mask, const float* __restrict__ adj,
                            const int* __restrict__ layer, unsigned short* __restrict__ biasT){
  float sc = 1.0f/(float)(layer[0]+1);
  int i = blockIdx.x*blockDim.x + threadIdx.x;
  const int n4 = (BB*SS*SS)/4;
  for (; i < n4; i += gridDim.x*blockDim.x){
    i32x4 m = ((const i32x4*)mask)[i];
    f32x4 a = ((const f32x4*)adj)[i];
    u16x4 r;
    #pragma unroll
    for (int j=0;j<4;j++) r[j] = m[j] ? f2bf(a[j]*sc) : f2bf(-1e9f);
    const int e  = i*4;
    const int bb = e >> 18;
    const int qq = (e >> 9) & 511;
    const int kk = e & 511;
    const int idx = (((bb*32 + (qq>>4))*32 + (kk>>4))<<8) + ((qq&15)<<4) + (kk&15);
    *(u16x4*)(biasT + idx) = r;
  }
}

// ---------------- GEMM bodies (128x128, BK=32, 256 thr, dbuf) ----------------
#define BM 128
#define BN 128
#define BK 32

template<typename EPI>
__device__ inline void gemm_body(const unsigned short* __restrict__ A,
                                 const unsigned short* __restrict__ W,
                                 int m0, int n0, EPI&& epi)
{
  __shared__ unsigned short As[2][BM*BK];
  __shared__ unsigned short Ws[2][BN*BK];
  const int tid  = threadIdx.x;
  const int lane = tid & 63;
  const int wave = tid >> 6;
  const int wr   = (wave >> 1) * 64;
  const int wc   = (wave & 1) * 64;
  const int l15  = lane & 15;
  const int g    = lane >> 4;

  f32x4 acc[4][4];
  #pragma unroll
  for (int i=0;i<4;i++)
    #pragma unroll
    for (int j=0;j<4;j++){ f32x4 z = {0.f,0.f,0.f,0.f}; acc[i][j]=z; }

  const int srow  = (lane >> 2);
  const int sunit = (lane & 3) ^ ((lane >> 3) & 3);   // pre-swizzled source octet
  const unsigned short* Ag0 = A + (int64_t)(m0 + wave*32 + srow)*DD + sunit*8;
  const unsigned short* Ag1 = A + (int64_t)(m0 + wave*32 + 16 + srow)*DD + sunit*8;
  const unsigned short* Wg0 = W + (int64_t)(n0 + wave*32 + srow)*DD + sunit*8;
  const unsigned short* Wg1 = W + (int64_t)(n0 + wave*32 + 16 + srow)*DD + sunit*8;

  auto stage = [&](int buf, int k0){
    gload_lds16(Ag0 + k0, As[buf] + wave*1024);
    gload_lds16(Ag1 + k0, As[buf] + wave*1024 + 512);
    gload_lds16(Wg0 + k0, Ws[buf] + wave*1024);
    gload_lds16(Wg1 + k0, Ws[buf] + wave*1024 + 512);
  };

  const int fro = (g ^ ((l15 >> 1) & 3)) * 8;         // swizzled read offset

  stage(0, 0);
  int it = 0;
  for (int k0 = 0; k0 < DD; k0 += BK, it++){
    const int buf = it & 1;
    __syncthreads();               // stage(buf) landed; prior readers of buf^1 done
    if (k0 + BK < DD) stage(buf^1, k0 + BK);
    bf16x8 af[4], wf[4];
    #pragma unroll
    for (int m=0;m<4;m++) af[m] = *(const bf16x8*)&As[buf][(wr + m*16 + l15)*BK + fro];
    #pragma unroll
    for (int n=0;n<4;n++) wf[n] = *(const bf16x8*)&Ws[buf][(wc + n*16 + l15)*BK + fro];
    #pragma unroll
    for (int m=0;m<4;m++)
      #pragma unroll
      for (int n=0;n<4;n++)
        acc[m][n] = __builtin_amdgcn_mfma_f32_16x16x32_bf16(af[m], wf[n], acc[m][n], 0,0,0);
  }

  #pragma unroll
  for (int m=0;m<4;m++){
    const int rowbase = m0 + wr + m*16 + g*4;
    #pragma unroll
    for (int n=0;n<4;n++){
      const int col = n0 + wc + n*16 + l15;
      #pragma unroll
      for (int r=0;r<4;r++)
        epi(rowbase + r, col, acc[m][n][r]);
    }
  }
}

// merged QKV projection: grid (128, 15); y/5 selects {q,k,v}, y%5 selects n-tile
__global__ __launch_bounds__(256)
void qkv_gemm(const unsigned short* __restrict__ Xq, const unsigned short* __restrict__ Xk,
              const unsigned short* __restrict__ Xv,
              const unsigned short* __restrict__ bWq, const unsigned short* __restrict__ bWk,
              const unsigned short* __restrict__ bWv,
              const float* __restrict__ bq, const float* __restrict__ bk,
              const float* __restrict__ bv,
              unsigned short* __restrict__ qbuf, unsigned short* __restrict__ kbuf,
              unsigned short* __restrict__ vTbuf)
{
  const int y   = blockIdx.y;
  const int sel = y / 5;
  const int n0  = (y % 5) * BN;
  const int m0  = blockIdx.x * BM;
  const unsigned short* A = sel==0 ? Xq  : sel==1 ? Xk  : Xv;
  const unsigned short* W = sel==0 ? bWq : sel==1 ? bWk : bWv;
  const float*          bb= sel==0 ? bq  : sel==1 ? bk  : bv;
  unsigned short* outp    = sel==0 ? qbuf : kbuf;

  gemm_body(A, W, m0, n0, [&](int row, int col, float v){
    float val = v + bb[col];
    int b=row>>9, s=row&511, h=col>>6, dk=col&63;
    if (sel < 2)
      outp[(((int64_t)(b*HH + h))*SS + s)*DKK + dk] = f2bf(val);
    else
      vTbuf[(((int64_t)(b*HH + h))*DKK + dk)*SS + s] = f2bf(val);
  });
}

// final routing GEMM: out[n,o] = sum_k xw[n,k] * bRWT[o,k]  (f32 out = final answer)
__global__ __launch_bounds__(256)
void final_gemm(const unsigned short* __restrict__ A, const unsigned short* __restrict__ W,
                float* __restrict__ outp)
{
  gemm_body(A, W, blockIdx.x*BM, blockIdx.y*BN, [&](int row, int col, float v){
    outp[(int64_t)row*DD + col] = v;
  });
}

// ---------------- attention (unchanged from R8) ----------------
__global__ __launch_bounds__(256)
void attn_kernel(const unsigned short* __restrict__ qb, const unsigned short* __restrict__ kb,
                 const unsigned short* __restrict__ vT, const unsigned short* __restrict__ biasT,
                 unsigned short* __restrict__ xout)
{
  __shared__ unsigned short SH[20480];   // 40KB: K 2x8KB | V 2x8KB | P 4x2KB
  unsigned short* Kl = SH;               // [2][4096]
  unsigned short* Vl = SH + 8192;        // [2][4096]
  char* Pall = (char*)(SH + 16384);

  const int tid  = threadIdx.x;
  const int lane = tid & 63;
  const int wave = tid >> 6;
  const int l15  = lane & 15;
  const int g    = lane >> 4;

  const int orig = blockIdx.x;
  const int wgid = (orig & 7)*320 + (orig >> 3);   // XCD-chunk swizzle
  const int h  = wgid % 10;
  const int qt = (wgid / 10) & 7;
  const int b  = wgid / 80;
  const int bh = b*HH + h;

  const unsigned short* Q  = qb + (int64_t)bh*SS*DKK;
  const unsigned short* K  = kb + (int64_t)bh*SS*DKK;
  const unsigned short* V  = vT + (int64_t)bh*DKK*SS;
  const unsigned short* Bt = biasT + (int64_t)((b*32 + qt*4 + wave)*32)*256
                           + l15*16 + g*4;

  const int q0 = qt*64 + wave*16;
  char* Pb = Pall + wave*2048;           // 16 rows x 128B

  const int srow8 = lane >> 3;
  const int sunit = (lane & 7) ^ (srow8 & 7);

  bf16x8 qf[2];
  #pragma unroll
  for (int ks=0; ks<2; ks++)
    qf[ks] = *(const bf16x8*)(Q + (q0 + l15)*DKK + ks*32 + g*8);

  auto stage = [&](int c, int buf){
    #pragma unroll
    for (int c2=0;c2<2;c2++){
      const int i = wave*2 + c2;                      // 0..7 across waves
      gload_lds16(K + (int64_t)(c*64 + i*8 + srow8)*DKK + sunit*8,
                  Kl + buf*4096 + i*512);
      gload_lds16(V + (int64_t)(i*8 + srow8)*SS + c*64 + sunit*8,
                  Vl + buf*4096 + i*512);
    }
  };

  float lsum = 0.f;
  f32x4 oacc[4];
  #pragma unroll
  for (int n=0;n<4;n++){ f32x4 z={0.f,0.f,0.f,0.f}; oacc[n]=z; }

  u16x4 bvc[4], bvn[4];
  #pragma unroll
  for (int j=0;j<4;j++) bvc[j] = *(const u16x4*)(Bt + j*256);

  stage(0, 0);
  for (int c = 0; c < 8; c++){
    const int buf = c & 1;
    __syncthreads();                     // stage(c) landed; buf^1 readers done
    if (c < 7){
      stage(c+1, buf^1);
      #pragma unroll
      for (int j=0;j<4;j++) bvn[j] = *(const u16x4*)(Bt + ((c+1)*4 + j)*256);
    }

    f32x4 sc[4];
    #pragma unroll
    for (int j=0;j<4;j++){ f32x4 z={0.f,0.f,0.f,0.f}; sc[j]=z; }
    #pragma unroll
    for (int ks=0; ks<2; ks++){
      #pragma unroll
      for (int j=0;j<4;j++){
        bf16x8 kf = *(const bf16x8*)((char*)(Kl + buf*4096)
                     + (j*16 + l15)*128 + (((ks*4+g) ^ (l15&7))*16));
        sc[j] = __builtin_amdgcn_mfma_f32_16x16x32_bf16(kf, qf[ks], sc[j], 0,0,0);
      }
    }
    #pragma unroll
    for (int j=0;j<4;j++){
      float p[4];
      #pragma unroll
      for (int r=0;r<4;r++){
        float s = __builtin_fmaf(sc[j][r], 0.125f, bf2f(bvc[j][r]));
        p[r] = __expf(s - 8.0f);
        lsum += p[r];
      }
      unsigned int w0 = cvtpk_bf16(p[0], p[1]);
      unsigned int w1 = cvtpk_bf16(p[2], p[3]);
      const int kk = j*16 + g*4;
      const int sw = (kk >> 3) ^ (l15 & 7);
      u32x2 w; w[0]=w0; w[1]=w1;
      *(u32x2*)(Pb + l15*128 + sw*16 + (kk&7)*2) = w;
    }
    #pragma unroll
    for (int kt=0; kt<2; kt++){
      bf16x8 pf = *(const bf16x8*)(Pb + l15*128 + (((kt*4+g) ^ (l15&7))*16));
      #pragma unroll
      for (int n=0;n<4;n++){
        bf16x8 vf = *(const bf16x8*)((char*)(Vl + buf*4096)
                     + (n*16 + l15)*128 + (((kt*4+g) ^ (l15&7))*16));
        oacc[n] = __builtin_amdgcn_mfma_f32_16x16x32_bf16(pf, vf, oacc[n], 0,0,0);
      }
    }
    #pragma unroll
    for (int j=0;j<4;j++) bvc[j] = bvn[j];
  }

  lsum += __shfl_xor(lsum, 16);
  lsum += __shfl_xor(lsum, 32);
  const float inv = 1.0f / lsum;          // valid for q=l15
  float invr[4];
  #pragma unroll
  for (int r=0;r<4;r++) invr[r] = __shfl(inv, g*4 + r);

  #pragma unroll
  for (int n=0;n<4;n++){
    const int dk = n*16 + l15;
    #pragma unroll
    for (int r=0;r<4;r++){
      const int qrow = q0 + g*4 + r;
      const int ntok = b*SS + qrow;
      xout[(int64_t)ntok*DD + h*DKK + dk] = f2bf(oacc[n][r] * invr[r]);
    }
  }
}

// ---------------- gram routing kernel ----------------
// Per block: 16 tokens. priors tiles via MFMA (f32), Gram G[10][10] per token on
// VALU, 3-iteration routing recurrence in-block, emits xw = x * (sc2*probs2)[head].
// Final out = xw @ bRWT^T (final_gemm).
__global__ __launch_bounds__(256)
void gram_kernel(const unsigned short* __restrict__ x,
                 const unsigned short* __restrict__ RWT,
                 unsigned short* __restrict__ xw)
{
  __shared__ unsigned short Xl[16*664];   // padded rows (stride 664 elems, 2-way max)
  __shared__ float Gp[4][16][56];
  __shared__ float Gfin[16][56];
  __shared__ float Pr[16][10];
  __shared__ float Dm[16][10];
  __shared__ float Lg[16][10];
  __shared__ float wl[16][10];

  const int tid  = threadIdx.x;
  const int lane = tid & 63;
  const int wave = tid >> 6;
  const int l15  = lane & 15;
  const int g    = lane >> 4;
  const int tok0 = blockIdx.x * 16;

  // stage x[16][640] -> padded LDS
  #pragma unroll
  for (int rd=0; rd<5; rd++){
    const int idx = rd*2048 + tid*8;
    const int tk  = idx / 640;
    const int cl  = idx - tk*640;
    u32x4 vv = *(const u32x4*)(x + (int64_t)tok0*640 + idx);
    *(u32x4*)&Xl[tk*664 + cl] = vv;
  }
  __syncthreads();

  float Gacc[55];
  #pragma unroll
  for (int p=0;p<55;p++) Gacc[p]=0.f;

  for (int ot=0; ot<10; ot++){            // wave's o-tiles: o = (wave*10+ot)*16
    const int o0 = (wave*10 + ot)*16;
    f32x4 P[10];
    #pragma unroll
    for (int r=0;r<10;r++){ f32x4 z={0.f,0.f,0.f,0.f}; P[r]=z; }
    #pragma unroll
    for (int r=0;r<10;r++){
      #pragma unroll
      for (int ks=0;ks<2;ks++){
        bf16x8 af = *(const bf16x8*)&RWT[(int64_t)(o0+l15)*DD + r*64 + ks*32 + g*8];
        bf16x8 xf = *(const bf16x8*)&Xl[l15*664 + r*64 + ks*32 + g*8];
        P[r] = __builtin_amdgcn_mfma_f32_16x16x32_bf16(af, xf, P[r], 0,0,0);
      }
    }
    // lane holds P[r][tok=l15][o = o0 + g*4 + e]; Gram partial (upper triangle)
    #pragma unroll
    for (int r=0;r<10;r++)
      #pragma unroll
      for (int rp=r; rp<10; rp++){
        const int T = r*10 - r*(r-1)/2 + (rp-r);
        Gacc[T] += P[r][0]*P[rp][0] + P[r][1]*P[rp][1]
                 + P[r][2]*P[rp][2] + P[r][3]*P[rp][3];
      }
  }
  #pragma unroll
  for (int p=0;p<55;p++){
    Gacc[p] += __shfl_xor(Gacc[p], 16);
    Gacc[p] += __shfl_xor(Gacc[p], 32);
  }
  if (lane < 16){
    #pragma unroll
    for (int p=0;p<55;p++) Gp[wave][lane][p] = Gacc[p];
  }
  __syncthreads();
  {
    const int gtok = tid & 15;
    for (int p = tid>>4; p < 55; p += 16)
      Gfin[gtok][p] = Gp[0][gtok][p]+Gp[1][gtok][p]+Gp[2][gtok][p]+Gp[3][gtok][p];
  }
  __syncthreads();

  // routing recurrence: thread (tok, r'), 10 active per token
  const int tok = tid >> 4, rp = tid & 15;
  const bool act = rp < 10;
  float grow[10]; float Lr = 0.f;
  if (act){
    #pragma unroll
    for (int r=0;r<10;r++){
      const int lo = r < rp ? r : rp, hi = r < rp ? rp : r;
      grow[r] = Gfin[tok][lo*10 - lo*(lo-1)/2 + (hi-lo)];
    }
    Pr[tok][rp] = 0.1f;
  }
  __syncthreads();
  for (int it=0; it<3; it++){
    float d = 0.f;
    if (act){
      #pragma unroll
      for (int r=0;r<10;r++) d += grow[r]*Pr[tok][r];
      Dm[tok][rp] = d;
    }
    __syncthreads();
    if (act){
      float sn = 0.f;
      #pragma unroll
      for (int r=0;r<10;r++) sn += Dm[tok][r]*Pr[tok][r];
      const float sc = (sn/(1.f+sn))*rsqrtf(sn+1e-9f);
      if (it < 2){ Lr += sc*d; Lg[tok][rp] = Lr; }
      else        wl[tok][rp] = sc*Pr[tok][rp];
    }
    __syncthreads();
    if (it < 2){
      if (act){
        float mx = Lg[tok][0];
        #pragma unroll
        for (int r=1;r<10;r++) mx = fmaxf(mx, Lg[tok][r]);
        float se = 0.f;
        #pragma unroll
        for (int r=0;r<10;r++) se += __expf(Lg[tok][r]-mx);
        Pr[tok][rp] = __expf(Lr-mx)/se;
      }
      __syncthreads();
    }
  }

  // xw[tok][c] = x[tok][c] * w[tok][c>>6]
  {
    const int tk = tid >> 4, seg = tid & 15;
    #pragma unroll
    for (int j=0;j<5;j++){
      const int c = seg*40 + j*8;
      const float w = wl[tk][c>>6];
      u16x4 a = *(const u16x4*)&Xl[tk*664 + c];
      u16x4 b = *(const u16x4*)&Xl[tk*664 + c + 4];
      u32x4 o;
      o[0] = cvtpk_bf16(bf2f(a[0])*w, bf2f(a[1])*w);
      o[1] = cvtpk_bf16(bf2f(a[2])*w, bf2f(a[3])*w);
      o[2] = cvtpk_bf16(bf2f(b[0])*w, bf2f(b[1])*w);
      o[3] = cvtpk_bf16(bf2f(b[2])*w, bf2f(b[3])*w);
      *(u32x4*)&xw[(int64_t)(tok0+tk)*DD + c] = o;
    }
  }
}

// ---------------- launch ----------------
extern "C" void kernel_launch(void* const* d_in, const int* in_sizes, int n_in,
                              void* d_out, int out_size, void* d_ws, size_t ws_size,
                              hipStream_t stream)
{
  (void)in_sizes; (void)n_in; (void)out_size; (void)ws_size;
  const float* q    = (const float*)d_in[0];
  const float* k    = (const float*)d_in[1];
  const float* v    = (const float*)d_in[2];
  const int*   mask = (const int*)d_in[3];
  const float* adj  = (const float*)d_in[4];
  const int*   layer= (const int*)d_in[5];
  const float* Wq   = (const float*)d_in[6];
  const float* bq   = (const float*)d_in[7];
  const float* Wk   = (const float*)d_in[8];
  const float* bk   = (const float*)d_in[9];
  const float* Wv   = (const float*)d_in[10];
  const float* bv   = (const float*)d_in[11];
  const float* rw   = (const float*)d_in[12];

  char* ws = (char*)d_ws;
  size_t off = 0;
  auto alloc = [&](size_t sz)->char*{ char* p = ws + off; off += (sz + 255) & ~(size_t)255; return p; };
  const size_t SZX = (size_t)NTOK*DD*2;
  unsigned short* Xq    = (unsigned short*)alloc(SZX);
  unsigned short* Xk    = (unsigned short*)alloc(SZX);
  unsigned short* Xv    = (unsigned short*)alloc(SZX);
  unsigned short* bWq   = (unsigned short*)alloc((size_t)DD*DD*2);
  unsigned short* bWk   = (unsigned short*)alloc((size_t)DD*DD*2);
  unsigned short* bWv   = (unsigned short*)alloc((size_t)DD*DD*2);
  unsigned short* bRWT  = (unsigned short*)alloc((size_t)DD*DD*2);
  unsigned short* qbuf  = (unsigned short*)alloc(SZX);
  unsigned short* kbuf  = (unsigned short*)alloc(SZX);
  unsigned short* vTbuf = (unsigned short*)alloc(SZX);
  unsigned short* biasb = (unsigned short*)alloc((size_t)BB*SS*SS*2);
  // aliases (provably dead at reuse time, stream-ordered):
  unsigned short* xout  = Xq;    // Xq dead after q-projection
  unsigned short* xw    = Xk;    // Xk dead after k-projection

  convert_qkv<<<2048,256,0,stream>>>(q,k,v,Xq,Xk,Xv);
  convert_w<<<1600,256,0,stream>>>(Wq,Wk,Wv,rw,bWq,bWk,bWv,bRWT);
  bias_kernel<<<2048,256,0,stream>>>(mask,adj,layer,biasb);

  dim3 gq(NTOK/BM, 15);
  qkv_gemm<<<gq,256,0,stream>>>(Xq,Xk,Xv,bWq,bWk,bWv,bq,bk,bv,qbuf,kbuf,vTbuf);

  attn_kernel<<<2560,256,0,stream>>>(qbuf,kbuf,vTbuf,biasb,xout);

  gram_kernel<<<NTOK/16,256,0,stream>>>(xout,bRWT,xw);

  dim3 gf(NTOK/BM, DD/BN);
  final_gemm<<<gf,256,0,stream>>>(xw,bRWT,(float*)d_out);
}

// Round 10
// 298.523 us; speedup vs baseline: 1.3671x; 1.0889x over previous
//
#include <hip/hip_runtime.h>
#include <stdint.h>

#define BB 32
#define SS 512
#define DD 640
#define HH 10
#define DKK 64
#define NTOK (BB*SS)   // 16384

using f32x4  = __attribute__((ext_vector_type(4))) float;
using bf16x8 = __attribute__((ext_vector_type(8))) __bf16;
using u32x4  = __attribute__((ext_vector_type(4))) unsigned int;
using u32x2  = __attribute__((ext_vector_type(2))) unsigned int;
using u16x4  = __attribute__((ext_vector_type(4))) unsigned short;
using i32x4  = __attribute__((ext_vector_type(4))) int;

__device__ inline unsigned short f2bf(float f){
  union { float f; unsigned int u; } v; v.f=f;
  unsigned int u=v.u;
  u += 0x7FFFu + ((u>>16)&1u);
  return (unsigned short)(u>>16);
}
__device__ inline float bf2f(unsigned short s){
  union { unsigned int u; float f; } v; v.u = ((unsigned int)s)<<16;
  return v.f;
}
__device__ inline unsigned int cvtpk_bf16(float lo, float hi){
  unsigned int r;
  asm volatile("v_cvt_pk_bf16_f32 %0, %1, %2" : "=v"(r) : "v"(lo), "v"(hi));
  return r;
}
__device__ inline void gload_lds16(const unsigned short* g, unsigned short* l){
  __builtin_amdgcn_global_load_lds(
      (const __attribute__((address_space(1))) unsigned int*)g,
      (__attribute__((address_space(3))) unsigned int*)l, 16, 0, 0);
}

// ---------------- conversions ----------------
__global__ void convert_qkv(const float* __restrict__ q, const float* __restrict__ k,
                            const float* __restrict__ v,
                            unsigned short* __restrict__ xq, unsigned short* __restrict__ xk,
                            unsigned short* __restrict__ xv){
  int i = blockIdx.x*blockDim.x + threadIdx.x;
  const int n4 = (NTOK*DD)/4;
  for (; i < n4; i += gridDim.x*blockDim.x){
    f32x4 a = ((const f32x4*)q)[i];
    f32x4 b = ((const f32x4*)k)[i];
    f32x4 c = ((const f32x4*)v)[i];
    u16x4 ra, rb, rc;
    #pragma unroll
    for (int j=0;j<4;j++){ ra[j]=f2bf(a[j]); rb[j]=f2bf(b[j]); rc[j]=f2bf(c[j]); }
    ((u16x4*)xq)[i]=ra; ((u16x4*)xk)[i]=rb; ((u16x4*)xv)[i]=rc;
  }
}

// also packs RWT into fragment-linear layout for gram_part:
// RWTf[((oT*10 + r)*2 + ks)*512 + (g*16 + (o&15))*8 + j]
__global__ void convert_w(const float* __restrict__ wq, const float* __restrict__ wk,
                          const float* __restrict__ wv, const float* __restrict__ rw,
                          unsigned short* __restrict__ bwq, unsigned short* __restrict__ bwk,
                          unsigned short* __restrict__ bwv, unsigned short* __restrict__ brwt,
                          unsigned short* __restrict__ brwtf){
  int i = blockIdx.x*blockDim.x + threadIdx.x;
  if (i < DD*DD){
    bwq[i]=f2bf(wq[i]); bwk[i]=f2bf(wk[i]); bwv[i]=f2bf(wv[i]);
    unsigned short rv = f2bf(rw[i]);
    const int kk = i / DD;       // r*64 + ii
    const int o  = i % DD;
    brwt[o*DD + kk] = rv;        // final_gemm W operand (rows=o, cols=k)
    const int r  = kk >> 6, ii = kk & 63;
    const int ks = ii >> 5, rem = ii & 31, g = rem >> 3, j = rem & 7;
    const int oT = o >> 4, l15o = o & 15;
    brwtf[(size_t)((oT*10 + r)*2 + ks)*512 + (g*16 + l15o)*8 + j] = rv;
  }
}

// bias in 16x16-tile layout: biasT[((b*32 + q>>4)*32 + k>>4)*256 + (q&15)*16 + (k&15)]
__global__ void bias_kernel(const int* __restrict__ mask, const float* __restrict__ adj,
                            const int* __restrict__ layer, unsigned short* __restrict__ biasT){
  float sc = 1.0f/(float)(layer[0]+1);
  int i = blockIdx.x*blockDim.x + threadIdx.x;
  const int n4 = (BB*SS*SS)/4;
  for (; i < n4; i += gridDim.x*blockDim.x){
    i32x4 m = ((const i32x4*)mask)[i];
    f32x4 a = ((const f32x4*)adj)[i];
    u16x4 r;
    #pragma unroll
    for (int j=0;j<4;j++) r[j] = m[j] ? f2bf(a[j]*sc) : f2bf(-1e9f);
    const int e  = i*4;
    const int bb = e >> 18;
    const int qq = (e >> 9) & 511;
    const int kk = e & 511;
    const int idx = (((bb*32 + (qq>>4))*32 + (kk>>4))<<8) + ((qq&15)<<4) + (kk&15);
    *(u16x4*)(biasT + idx) = r;
  }
}

// ---------------- GEMM bodies (128x128, BK=32, 256 thr, dbuf) ----------------
#define BM 128
#define BN 128
#define BK 32

template<typename EPI>
__device__ inline void gemm_body(const unsigned short* __restrict__ A,
                                 const unsigned short* __restrict__ W,
                                 int m0, int n0, EPI&& epi)
{
  __shared__ unsigned short As[2][BM*BK];
  __shared__ unsigned short Ws[2][BN*BK];
  const int tid  = threadIdx.x;
  const int lane = tid & 63;
  const int wave = tid >> 6;
  const int wr   = (wave >> 1) * 64;
  const int wc   = (wave & 1) * 64;
  const int l15  = lane & 15;
  const int g    = lane >> 4;

  f32x4 acc[4][4];
  #pragma unroll
  for (int i=0;i<4;i++)
    #pragma unroll
    for (int j=0;j<4;j++){ f32x4 z = {0.f,0.f,0.f,0.f}; acc[i][j]=z; }

  const int srow  = (lane >> 2);
  const int sunit = (lane & 3) ^ ((lane >> 3) & 3);   // pre-swizzled source octet
  const unsigned short* Ag0 = A + (int64_t)(m0 + wave*32 + srow)*DD + sunit*8;
  const unsigned short* Ag1 = A + (int64_t)(m0 + wave*32 + 16 + srow)*DD + sunit*8;
  const unsigned short* Wg0 = W + (int64_t)(n0 + wave*32 + srow)*DD + sunit*8;
  const unsigned short* Wg1 = W + (int64_t)(n0 + wave*32 + 16 + srow)*DD + sunit*8;

  auto stage = [&](int buf, int k0){
    gload_lds16(Ag0 + k0, As[buf] + wave*1024);
    gload_lds16(Ag1 + k0, As[buf] + wave*1024 + 512);
    gload_lds16(Wg0 + k0, Ws[buf] + wave*1024);
    gload_lds16(Wg1 + k0, Ws[buf] + wave*1024 + 512);
  };

  const int fro = (g ^ ((l15 >> 1) & 3)) * 8;         // swizzled read offset

  stage(0, 0);
  int it = 0;
  for (int k0 = 0; k0 < DD; k0 += BK, it++){
    const int buf = it & 1;
    __syncthreads();               // stage(buf) landed; prior readers of buf^1 done
    if (k0 + BK < DD) stage(buf^1, k0 + BK);
    bf16x8 af[4], wf[4];
    #pragma unroll
    for (int m=0;m<4;m++) af[m] = *(const bf16x8*)&As[buf][(wr + m*16 + l15)*BK + fro];
    #pragma unroll
    for (int n=0;n<4;n++) wf[n] = *(const bf16x8*)&Ws[buf][(wc + n*16 + l15)*BK + fro];
    #pragma unroll
    for (int m=0;m<4;m++)
      #pragma unroll
      for (int n=0;n<4;n++)
        acc[m][n] = __builtin_amdgcn_mfma_f32_16x16x32_bf16(af[m], wf[n], acc[m][n], 0,0,0);
  }

  #pragma unroll
  for (int m=0;m<4;m++){
    const int rowbase = m0 + wr + m*16 + g*4;
    #pragma unroll
    for (int n=0;n<4;n++){
      const int col = n0 + wc + n*16 + l15;
      #pragma unroll
      for (int r=0;r<4;r++)
        epi(rowbase + r, col, acc[m][n][r]);
    }
  }
}

// merged QKV projection: grid (128, 15); y/5 selects {q,k,v}, y%5 selects n-tile
__global__ __launch_bounds__(256)
void qkv_gemm(const unsigned short* __restrict__ Xq, const unsigned short* __restrict__ Xk,
              const unsigned short* __restrict__ Xv,
              const unsigned short* __restrict__ bWq, const unsigned short* __restrict__ bWk,
              const unsigned short* __restrict__ bWv,
              const float* __restrict__ bq, const float* __restrict__ bk,
              const float* __restrict__ bv,
              unsigned short* __restrict__ qbuf, unsigned short* __restrict__ kbuf,
              unsigned short* __restrict__ vTbuf)
{
  const int y   = blockIdx.y;
  const int sel = y / 5;
  const int n0  = (y % 5) * BN;
  const int m0  = blockIdx.x * BM;
  const unsigned short* A = sel==0 ? Xq  : sel==1 ? Xk  : Xv;
  const unsigned short* W = sel==0 ? bWq : sel==1 ? bWk : bWv;
  const float*          bb= sel==0 ? bq  : sel==1 ? bk  : bv;
  unsigned short* outp    = sel==0 ? qbuf : kbuf;

  gemm_body(A, W, m0, n0, [&](int row, int col, float v){
    float val = v + bb[col];
    int b=row>>9, s=row&511, h=col>>6, dk=col&63;
    if (sel < 2)
      outp[(((int64_t)(b*HH + h))*SS + s)*DKK + dk] = f2bf(val);
    else
      vTbuf[(((int64_t)(b*HH + h))*DKK + dk)*SS + s] = f2bf(val);
  });
}

// final routing GEMM: out[n,o] = sum_k xw[n,k] * bRWT[o,k]  (f32 out = final answer)
__global__ __launch_bounds__(256)
void final_gemm(const unsigned short* __restrict__ A, const unsigned short* __restrict__ W,
                float* __restrict__ outp)
{
  gemm_body(A, W, blockIdx.x*BM, blockIdx.y*BN, [&](int row, int col, float v){
    outp[(int64_t)row*DD + col] = v;
  });
}

// ---------------- attention (unchanged from R8/R9) ----------------
__global__ __launch_bounds__(256)
void attn_kernel(const unsigned short* __restrict__ qb, const unsigned short* __restrict__ kb,
                 const unsigned short* __restrict__ vT, const unsigned short* __restrict__ biasT,
                 unsigned short* __restrict__ xout)
{
  __shared__ unsigned short SH[20480];   // 40KB: K 2x8KB | V 2x8KB | P 4x2KB
  unsigned short* Kl = SH;               // [2][4096]
  unsigned short* Vl = SH + 8192;        // [2][4096]
  char* Pall = (char*)(SH + 16384);

  const int tid  = threadIdx.x;
  const int lane = tid & 63;
  const int wave = tid >> 6;
  const int l15  = lane & 15;
  const int g    = lane >> 4;

  const int orig = blockIdx.x;
  const int wgid = (orig & 7)*320 + (orig >> 3);   // XCD-chunk swizzle
  const int h  = wgid % 10;
  const int qt = (wgid / 10) & 7;
  const int b  = wgid / 80;
  const int bh = b*HH + h;

  const unsigned short* Q  = qb + (int64_t)bh*SS*DKK;
  const unsigned short* K  = kb + (int64_t)bh*SS*DKK;
  const unsigned short* V  = vT + (int64_t)bh*DKK*SS;
  const unsigned short* Bt = biasT + (int64_t)((b*32 + qt*4 + wave)*32)*256
                           + l15*16 + g*4;

  const int q0 = qt*64 + wave*16;
  char* Pb = Pall + wave*2048;           // 16 rows x 128B

  const int srow8 = lane >> 3;
  const int sunit = (lane & 7) ^ (srow8 & 7);

  bf16x8 qf[2];
  #pragma unroll
  for (int ks=0; ks<2; ks++)
    qf[ks] = *(const bf16x8*)(Q + (q0 + l15)*DKK + ks*32 + g*8);

  auto stage = [&](int c, int buf){
    #pragma unroll
    for (int c2=0;c2<2;c2++){
      const int i = wave*2 + c2;                      // 0..7 across waves
      gload_lds16(K + (int64_t)(c*64 + i*8 + srow8)*DKK + sunit*8,
                  Kl + buf*4096 + i*512);
      gload_lds16(V + (int64_t)(i*8 + srow8)*SS + c*64 + sunit*8,
                  Vl + buf*4096 + i*512);
    }
  };

  float lsum = 0.f;
  f32x4 oacc[4];
  #pragma unroll
  for (int n=0;n<4;n++){ f32x4 z={0.f,0.f,0.f,0.f}; oacc[n]=z; }

  u16x4 bvc[4], bvn[4];
  #pragma unroll
  for (int j=0;j<4;j++) bvc[j] = *(const u16x4*)(Bt + j*256);

  stage(0, 0);
  for (int c = 0; c < 8; c++){
    const int buf = c & 1;
    __syncthreads();                     // stage(c) landed; buf^1 readers done
    if (c < 7){
      stage(c+1, buf^1);
      #pragma unroll
      for (int j=0;j<4;j++) bvn[j] = *(const u16x4*)(Bt + ((c+1)*4 + j)*256);
    }

    f32x4 sc[4];
    #pragma unroll
    for (int j=0;j<4;j++){ f32x4 z={0.f,0.f,0.f,0.f}; sc[j]=z; }
    #pragma unroll
    for (int ks=0; ks<2; ks++){
      #pragma unroll
      for (int j=0;j<4;j++){
        bf16x8 kf = *(const bf16x8*)((char*)(Kl + buf*4096)
                     + (j*16 + l15)*128 + (((ks*4+g) ^ (l15&7))*16));
        sc[j] = __builtin_amdgcn_mfma_f32_16x16x32_bf16(kf, qf[ks], sc[j], 0,0,0);
      }
    }
    #pragma unroll
    for (int j=0;j<4;j++){
      float p[4];
      #pragma unroll
      for (int r=0;r<4;r++){
        float s = __builtin_fmaf(sc[j][r], 0.125f, bf2f(bvc[j][r]));
        p[r] = __expf(s - 8.0f);
        lsum += p[r];
      }
      unsigned int w0 = cvtpk_bf16(p[0], p[1]);
      unsigned int w1 = cvtpk_bf16(p[2], p[3]);
      const int kk = j*16 + g*4;
      const int sw = (kk >> 3) ^ (l15 & 7);
      u32x2 w; w[0]=w0; w[1]=w1;
      *(u32x2*)(Pb + l15*128 + sw*16 + (kk&7)*2) = w;
    }
    #pragma unroll
    for (int kt=0; kt<2; kt++){
      bf16x8 pf = *(const bf16x8*)(Pb + l15*128 + (((kt*4+g) ^ (l15&7))*16));
      #pragma unroll
      for (int n=0;n<4;n++){
        bf16x8 vf = *(const bf16x8*)((char*)(Vl + buf*4096)
                     + (n*16 + l15)*128 + (((kt*4+g) ^ (l15&7))*16));
        oacc[n] = __builtin_amdgcn_mfma_f32_16x16x32_bf16(pf, vf, oacc[n], 0,0,0);
      }
    }
    #pragma unroll
    for (int j=0;j<4;j++) bvc[j] = bvn[j];
  }

  lsum += __shfl_xor(lsum, 16);
  lsum += __shfl_xor(lsum, 32);
  const float inv = 1.0f / lsum;          // valid for q=l15
  float invr[4];
  #pragma unroll
  for (int r=0;r<4;r++) invr[r] = __shfl(inv, g*4 + r);

  #pragma unroll
  for (int n=0;n<4;n++){
    const int dk = n*16 + l15;
    #pragma unroll
    for (int r=0;r<4;r++){
      const int qrow = q0 + g*4 + r;
      const int ntok = b*SS + qrow;
      xout[(int64_t)ntok*DD + h*DKK + dk] = f2bf(oacc[n][r] * invr[r]);
    }
  }
}

// ---------------- gram partial kernel ----------------
// grid (NTOK/16, 5): block = 16 tokens x o-chunk oc (128 o-rows; wave: 2 o-tiles).
// P via MFMA on packed RWTf (coalesced 1KB frag loads); Gram partial on VALU;
// cross-wave sum -> Gpart[oc][tok][56] f32.
__global__ __launch_bounds__(256)
void gram_part(const unsigned short* __restrict__ x,
               const unsigned short* __restrict__ RWTf,
               float* __restrict__ Gpart)
{
  __shared__ unsigned short Xl[16*664];   // padded rows
  __shared__ float Gp[4][16][57];

  const int tid  = threadIdx.x;
  const int lane = tid & 63;
  const int wave = tid >> 6;
  const int l15  = lane & 15;
  const int g    = lane >> 4;
  const int tok0 = blockIdx.x * 16;
  const int oc   = blockIdx.y;

  #pragma unroll
  for (int rd=0; rd<5; rd++){
    const int idx = rd*2048 + tid*8;
    const int tk  = idx / 640;
    const int cl  = idx - tk*640;
    u32x4 vv = *(const u32x4*)(x + (int64_t)tok0*640 + idx);
    *(u32x4*)&Xl[tk*664 + cl] = vv;
  }
  __syncthreads();

  float Gacc[55];
  #pragma unroll
  for (int p=0;p<55;p++) Gacc[p]=0.f;

  #pragma unroll
  for (int ot2=0; ot2<2; ot2++){
    const int oTile = oc*8 + wave*2 + ot2;
    const unsigned short* base = RWTf + (size_t)oTile*10240;  // 10*2*512
    f32x4 P[10];
    #pragma unroll
    for (int r=0;r<10;r++){ f32x4 z={0.f,0.f,0.f,0.f}; P[r]=z; }
    #pragma unroll
    for (int r=0;r<10;r++){
      #pragma unroll
      for (int ks=0;ks<2;ks++){
        bf16x8 af = *(const bf16x8*)&base[(r*2+ks)*512 + lane*8];   // coalesced 1KB
        bf16x8 xf = *(const bf16x8*)&Xl[l15*664 + r*64 + ks*32 + g*8];
        P[r] = __builtin_amdgcn_mfma_f32_16x16x32_bf16(af, xf, P[r], 0,0,0);
      }
    }
    #pragma unroll
    for (int r=0;r<10;r++)
      #pragma unroll
      for (int rp=r; rp<10; rp++){
        const int T = r*10 - r*(r-1)/2 + (rp-r);
        Gacc[T] += P[r][0]*P[rp][0] + P[r][1]*P[rp][1]
                 + P[r][2]*P[rp][2] + P[r][3]*P[rp][3];
      }
  }
  #pragma unroll
  for (int p=0;p<55;p++){
    Gacc[p] += __shfl_xor(Gacc[p], 16);
    Gacc[p] += __shfl_xor(Gacc[p], 32);
  }
  if (lane < 16){
    #pragma unroll
    for (int p=0;p<55;p++) Gp[wave][lane][p] = Gacc[p];
  }
  __syncthreads();
  {
    const int gtok = tid & 15;
    for (int p = tid>>4; p < 55; p += 16)
      Gpart[((size_t)oc*NTOK + tok0 + gtok)*56 + p]
        = Gp[0][gtok][p]+Gp[1][gtok][p]+Gp[2][gtok][p]+Gp[3][gtok][p];
  }
}

// ---------------- routing recurrence + xw ----------------
// block = 16 tokens: sum 5 Gram partials, 3-iteration recurrence, xw = x*w (coalesced)
__global__ __launch_bounds__(256)
void route_xw(const float* __restrict__ Gpart, const unsigned short* __restrict__ x,
              unsigned short* __restrict__ xw)
{
  __shared__ float Gfin[16][57];
  __shared__ float Pr[16][10];
  __shared__ float Dm[16][10];
  __shared__ float Lg[16][10];
  __shared__ float wl[16][10];

  const int tid  = threadIdx.x;
  const int tok0 = blockIdx.x * 16;

  {
    const int gtok = tid & 15;
    for (int p = tid>>4; p < 55; p += 16){
      float s = 0.f;
      #pragma unroll
      for (int oc=0; oc<5; oc++)
        s += Gpart[((size_t)oc*NTOK + tok0 + gtok)*56 + p];
      Gfin[gtok][p] = s;
    }
  }
  __syncthreads();

  const int tok = tid >> 4, rp = tid & 15;
  const bool act = rp < 10;
  float grow[10]; float Lr = 0.f;
  if (act){
    #pragma unroll
    for (int r=0;r<10;r++){
      const int lo = r < rp ? r : rp, hi = r < rp ? rp : r;
      grow[r] = Gfin[tok][lo*10 - lo*(lo-1)/2 + (hi-lo)];
    }
    Pr[tok][rp] = 0.1f;
  }
  __syncthreads();
  for (int it=0; it<3; it++){
    float d = 0.f;
    if (act){
      #pragma unroll
      for (int r=0;r<10;r++) d += grow[r]*Pr[tok][r];
      Dm[tok][rp] = d;
    }
    __syncthreads();
    if (act){
      float sn = 0.f;
      #pragma unroll
      for (int r=0;r<10;r++) sn += Dm[tok][r]*Pr[tok][r];
      const float sc = (sn/(1.f+sn))*rsqrtf(sn+1e-9f);
      if (it < 2){ Lr += sc*d; Lg[tok][rp] = Lr; }
      else        wl[tok][rp] = sc*Pr[tok][rp];
    }
    __syncthreads();
    if (it < 2){
      if (act){
        float mx = Lg[tok][0];
        #pragma unroll
        for (int r=1;r<10;r++) mx = fmaxf(mx, Lg[tok][r]);
        float se = 0.f;
        #pragma unroll
        for (int r=0;r<10;r++) se += __expf(Lg[tok][r]-mx);
        Pr[tok][rp] = __expf(Lr-mx)/se;
      }
      __syncthreads();
    }
  }

  // xw = x * w, fully coalesced 8-elem chunks (chunk never crosses a 64-col head seg)
  #pragma unroll
  for (int e=0; e<5; e++){
    const int idx = e*2048 + tid*8;
    const int tk  = idx / 640;
    const int cl  = idx - tk*640;
    const float w = wl[tk][cl>>6];
    u16x4 a = *(const u16x4*)(x + (int64_t)tok0*640 + idx);
    u16x4 b = *(const u16x4*)(x + (int64_t)tok0*640 + idx + 4);
    u32x4 o;
    o[0] = cvtpk_bf16(bf2f(a[0])*w, bf2f(a[1])*w);
    o[1] = cvtpk_bf16(bf2f(a[2])*w, bf2f(a[3])*w);
    o[2] = cvtpk_bf16(bf2f(b[0])*w, bf2f(b[1])*w);
    o[3] = cvtpk_bf16(bf2f(b[2])*w, bf2f(b[3])*w);
    *(u32x4*)&xw[(int64_t)tok0*640 + idx] = o;
  }
}

// ---------------- launch ----------------
extern "C" void kernel_launch(void* const* d_in, const int* in_sizes, int n_in,
                              void* d_out, int out_size, void* d_ws, size_t ws_size,
                              hipStream_t stream)
{
  (void)in_sizes; (void)n_in; (void)out_size; (void)ws_size;
  const float* q    = (const float*)d_in[0];
  const float* k    = (const float*)d_in[1];
  const float* v    = (const float*)d_in[2];
  const int*   mask = (const int*)d_in[3];
  const float* adj  = (const float*)d_in[4];
  const int*   layer= (const int*)d_in[5];
  const float* Wq   = (const float*)d_in[6];
  const float* bq   = (const float*)d_in[7];
  const float* Wk   = (const float*)d_in[8];
  const float* bk   = (const float*)d_in[9];
  const float* Wv   = (const float*)d_in[10];
  const float* bv   = (const float*)d_in[11];
  const float* rw   = (const float*)d_in[12];

  char* ws = (char*)d_ws;
  size_t off = 0;
  auto alloc = [&](size_t sz)->char*{ char* p = ws + off; off += (sz + 255) & ~(size_t)255; return p; };
  const size_t SZX = (size_t)NTOK*DD*2;
  unsigned short* Xq    = (unsigned short*)alloc(SZX);
  unsigned short* Xk    = (unsigned short*)alloc(SZX);
  unsigned short* Xv    = (unsigned short*)alloc(SZX);
  unsigned short* bWq   = (unsigned short*)alloc((size_t)DD*DD*2);
  unsigned short* bWk   = (unsigned short*)alloc((size_t)DD*DD*2);
  unsigned short* bWv   = (unsigned short*)alloc((size_t)DD*DD*2);
  unsigned short* bRWT  = (unsigned short*)alloc((size_t)DD*DD*2);
  unsigned short* bRWTf = (unsigned short*)alloc((size_t)DD*DD*2);
  unsigned short* qbuf  = (unsigned short*)alloc(SZX);
  unsigned short* kbuf  = (unsigned short*)alloc(SZX);
  unsigned short* vTbuf = (unsigned short*)alloc(SZX);
  unsigned short* biasb = (unsigned short*)alloc((size_t)BB*SS*SS*2);
  float*          Gpart = (float*)alloc((size_t)5*NTOK*56*4);
  // aliases (provably dead at reuse time, stream-ordered):
  unsigned short* xout  = Xq;    // Xq dead after q-projection
  unsigned short* xw    = Xk;    // Xk dead after k-projection

  convert_qkv<<<2048,256,0,stream>>>(q,k,v,Xq,Xk,Xv);
  convert_w<<<1600,256,0,stream>>>(Wq,Wk,Wv,rw,bWq,bWk,bWv,bRWT,bRWTf);
  bias_kernel<<<2048,256,0,stream>>>(mask,adj,layer,biasb);

  dim3 gq(NTOK/BM, 15);
  qkv_gemm<<<gq,256,0,stream>>>(Xq,Xk,Xv,bWq,bWk,bWv,bq,bk,bv,qbuf,kbuf,vTbuf);

  attn_kernel<<<2560,256,0,stream>>>(qbuf,kbuf,vTbuf,biasb,xout);

  dim3 gp(NTOK/16, 5);
  gram_part<<<gp,256,0,stream>>>(xout,bRWTf,Gpart);
  route_xw<<<NTOK/16,256,0,stream>>>(Gpart,xout,xw);

  dim3 gf(NTOK/BM, DD/BN);
  final_gemm<<<gf,256,0,stream>>>(xw,bRWT,(float*)d_out);
}